// Round 2
// baseline (790.837 us; speedup 1.0000x reference)
//
#include <hip/hip_runtime.h>
#include <math.h>
#include <float.h>
#include <limits.h>

#define BNUM 2
#define V0 4096
#define V1N 1024
#define V2N 256
#define SUPN 7

typedef float float4v __attribute__((ext_vector_type(4)));

__device__ __forceinline__ float fast_silu(float x){
  return __fdividef(x, 1.0f + __expf(-x));
}

// ---------------- fused column-normalize for all 5 direction banks ----------------
__global__ void colnorm_all_k(const float* __restrict__ d0, const float* __restrict__ dir1,
                              const float* __restrict__ dir2, const float* __restrict__ dir3,
                              const float* __restrict__ dir4,
                              float* __restrict__ cn0, float* __restrict__ cn1,
                              float* __restrict__ cn2, float* __restrict__ cn3,
                              float* __restrict__ cn4){
  int c = blockIdx.x*256 + threadIdx.x;   // 0..8959
  const float* s; float* o; int nc;
  if(c < 896){ s=d0; o=cn0; nc=896; }
  else if((c-=896) < 896){ s=dir1; o=cn1; nc=896; }
  else if((c-=896) < 1792){ s=dir2; o=cn2; nc=1792; }
  else if((c-=1792) < 1792){ s=dir3; o=cn3; nc=1792; }
  else { c-=1792; if(c>=3584) return; s=dir4; o=cn4; nc=3584; }
  float a=s[c], b=s[nc+c], e=s[2*nc+c];
  float n=sqrtf(a*a+b*b+e*e); n=fmaxf(n,1e-12f);
  o[c]=a/n; o[nc+c]=b/n; o[2*nc+c]=e/n;
}

// ---------------- self-KNN (k=10, skip self): one wave per query ----------------
// pts: (B, VC, 3). Exact top-11 by (d, idx) lex order via per-lane top-4 pool +
// 11 shuffle-reduce extraction rounds; rare in-wave exact fallback.
template<int VC>
__global__ __launch_bounds__(256) void knn10_k(const float* __restrict__ pts,
    int* __restrict__ out_idx, float* __restrict__ out_dirn)
{
  constexpr int CHUNK = VC/64;
  constexpr int TOT = 11;
  int lane = threadIdx.x & 63;
  int wv   = threadIdx.x >> 6;
  int b = blockIdx.y;
  int j = blockIdx.x*4 + wv;
  const float* pb = pts + (size_t)b*VC*3;
  float qx=pb[3*j], qy=pb[3*j+1], qz=pb[3*j+2];
  float qs=qx*qx+qy*qy+qz*qz;

  float t0=FLT_MAX,t1=FLT_MAX,t2=FLT_MAX,t3=FLT_MAX;
  int   i0=INT_MAX,i1=INT_MAX,i2=INT_MAX,i3=INT_MAX;
  #pragma unroll 4
  for(int c=0;c<CHUNK;c++){
    int i = c*64 + lane;
    float cx=pb[3*i], cy=pb[3*i+1], cz=pb[3*i+2];
    float cs=cx*cx+cy*cy+cz*cz;
    float dt=qx*cx+qy*cy+qz*cz;
    float d=qs+cs-2.0f*dt;
    if(d<t3){
      if(d<t2){ t3=t2;i3=i2;
        if(d<t1){ t2=t1;i2=i1;
          if(d<t0){ t1=t0;i1=i0; t0=d;i0=i; }
          else    { t1=d;i1=i; }
        } else   { t2=d;i2=i; }
      } else     { t3=d;i3=i; }
    }
  }
  // extraction: enumerate pool in (d,idx)-ascending order
  float pd=-FLT_MAX; int pi=-1;
  int wi=0;
  for(int sel=0; sel<TOT; ++sel){
    bool g0=(t0>pd)||(t0==pd&&i0>pi);
    bool g1=(t1>pd)||(t1==pd&&i1>pi);
    bool g2=(t2>pd)||(t2==pd&&i2>pi);
    bool g3=(t3>pd)||(t3==pd&&i3>pi);
    float cd = g0?t0:(g1?t1:(g2?t2:(g3?t3:FLT_MAX)));
    int   ci = g0?i0:(g1?i1:(g2?i2:(g3?i3:INT_MAX)));
    #pragma unroll
    for(int s=32;s;s>>=1){
      float od=__shfl_xor(cd,s);
      int   oi=__shfl_xor(ci,s);
      if(od<cd || (od==cd && oi<ci)){cd=od;ci=oi;}
    }
    if(lane==sel) wi=ci;
    pd=cd; pi=ci;
  }
  // exactness guard: if my 4th-best was selected, my unseen 5th might belong
  bool bad = (t3<pd) || (t3==pd && i3<=pi);
  if(__any(bad)){
    pd=-FLT_MAX; pi=-1;
    for(int sel=0; sel<TOT; ++sel){
      float cd=FLT_MAX; int ci=INT_MAX;
      for(int c=0;c<CHUNK;c++){
        int i=c*64+lane;
        float cx=pb[3*i], cy=pb[3*i+1], cz=pb[3*i+2];
        float cs=cx*cx+cy*cy+cz*cz;
        float dt=qx*cx+qy*cy+qz*cz;
        float d=qs+cs-2.0f*dt;
        bool ok = ((d>pd)||(d==pd&&i>pi)) && ((d<cd)||(d==cd&&i<ci));
        if(ok){cd=d;ci=i;}
      }
      #pragma unroll
      for(int s=32;s;s>>=1){
        float od=__shfl_xor(cd,s);
        int   oi=__shfl_xor(ci,s);
        if(od<cd || (od==cd && oi<ci)){cd=od;ci=oi;}
      }
      if(lane==sel) wi=ci;
      pd=cd; pi=ci;
    }
  }
  if(lane>=1 && lane<TOT){
    size_t obase=((size_t)b*VC+j)*10 + (lane-1);
    out_idx[obase]=wi;
    float dx=pb[3*wi]-qx, dy=pb[3*wi+1]-qy, dz=pb[3*wi+2]-qz;
    float n=sqrtf(dx*dx+dy*dy+dz*dz); n=fmaxf(n,1e-12f);
    out_dirn[obase*3]=dx/n; out_dirn[obase*3+1]=dy/n; out_dirn[obase*3+2]=dz/n;
  }
}

// ---------------- nearest (argmin, ties -> lower index): one wave per query ----------------
template<int VC>
__global__ __launch_bounds__(256) void nearest_k(
    const float* __restrict__ src,  // (B, VC, 3) candidates
    const float* __restrict__ tgt,  // (B, V0, 3) queries
    int* __restrict__ outp)         // (B, V0)
{
  constexpr int CHUNK = VC/64;
  int lane=threadIdx.x&63, wv=threadIdx.x>>6;
  int b=blockIdx.y; int j=blockIdx.x*4+wv;
  const float* qb=tgt+(size_t)b*V0*3;
  float qx=qb[3*j],qy=qb[3*j+1],qz=qb[3*j+2];
  float qs=qx*qx+qy*qy+qz*qz;
  const float* cb=src+(size_t)b*VC*3;
  float bd=FLT_MAX; int bi=INT_MAX;
  #pragma unroll 4
  for(int c=0;c<CHUNK;c++){
    int i=c*64+lane;
    float cx=cb[3*i],cy=cb[3*i+1],cz=cb[3*i+2];
    float cs=cx*cx+cy*cy+cz*cz;
    float dt=qx*cx+qy*cy+qz*cz;
    float d=qs+cs-2.0f*dt;
    if(d<bd || (d==bd && i<bi)){bd=d;bi=i;}
  }
  #pragma unroll
  for(int s=32;s;s>>=1){
    float od=__shfl_xor(bd,s);
    int   oi=__shfl_xor(bi,s);
    if(od<bd || (od==bd && oi<bi)){bd=od;bi=oi;}
  }
  if(lane==0) outp[(size_t)b*V0+j]=bi;
}

// ---------------- conv_surface + outer silu -> fm0 (C=128) ----------------
__global__ __launch_bounds__(128) void conv_surf_k(
    const float* __restrict__ dirn, const float* __restrict__ cnd,
    float* __restrict__ fm0)
{
  int b=blockIdx.y, i=blockIdx.x, t=threadIdx.x;
  __shared__ float sd[32];
  if(t<30) sd[t]=dirn[((size_t)(b*V0+i)*10)*3+t];
  __syncthreads();
  float acc=0.0f;
  for(int s=0;s<SUPN;s++){
    int col=s*128+t;
    float w0=cnd[col], w1c=cnd[896+col], w2c=cnd[1792+col];
    float m=-INFINITY;
    #pragma unroll
    for(int n=0;n<10;n++){
      float d=sd[3*n]*w0+sd[3*n+1]*w1c+sd[3*n+2]*w2c;
      m=fmaxf(m, fast_silu(d));
    }
    acc+=m;
  }
  fm0[(size_t)(b*V0+i)*128+t]=fast_silu(acc);
}

// ---------------- GEMM: C[M,N] = A[M,K] @ W[K,N] + bias[N] ----------------
// 128x64 tile, BK=16, 256 threads, 8x4 per thread. M%128==0, N%64==0, K%16==0.
__global__ __launch_bounds__(256) void gemm_bias_k(
    const float* __restrict__ A, const float* __restrict__ W,
    const float* __restrict__ bias, float* __restrict__ C,
    int M, int N, int K)
{
  __shared__ float As[16][132];   // [k][m]
  __shared__ float Bs[16][68];    // [k][n]
  int t=threadIdx.x;
  int bm=blockIdx.y*128, bn=blockIdx.x*64;
  int tx=t&15, ty=t>>4;
  float4v acc[8];
  #pragma unroll
  for(int i=0;i<8;i++) acc[i]=(float4v)(0.0f);
  int ar=t>>1, ak=(t&1)*8;
  int bk=t>>4, bc=(t&15)*4;
  for(int k0=0;k0<K;k0+=16){
    float4v a0=*(const float4v*)&A[(size_t)(bm+ar)*K + k0+ak];
    float4v a1=*(const float4v*)&A[(size_t)(bm+ar)*K + k0+ak+4];
    float4v bv=*(const float4v*)&W[(size_t)(k0+bk)*N + bn+bc];
    #pragma unroll
    for(int u=0;u<4;u++){ As[ak+u][ar]=a0[u]; As[ak+4+u][ar]=a1[u]; }
    *(float4v*)&Bs[bk][bc]=bv;
    __syncthreads();
    #pragma unroll
    for(int kk=0;kk<16;kk++){
      float4v av0=*(const float4v*)&As[kk][ty*8];
      float4v av1=*(const float4v*)&As[kk][ty*8+4];
      float4v bb=*(const float4v*)&Bs[kk][tx*4];
      #pragma unroll
      for(int i2=0;i2<4;i2++){
        acc[i2]   += av0[i2]*bb;
        acc[4+i2] += av1[i2]*bb;
      }
    }
    __syncthreads();
  }
  float4v biasv=*(const float4v*)&bias[bn+tx*4];
  #pragma unroll
  for(int i2=0;i2<8;i2++){
    int row = (i2<4) ? (ty*8+i2) : (ty*8+i2);
    *(float4v*)&C[(size_t)(bm+row)*N + bn+tx*4] = acc[i2]+biasv;
  }
}

// ---------------- conv_layer aggregate: out = center + sum_s max_n theta*support --------
__global__ void conv_agg_k(
    const float* __restrict__ feat, int Vb, int C, int NC,
    const float* __restrict__ dirn, const int* __restrict__ nbidx,
    const float* __restrict__ cnd, int ncol,
    float* __restrict__ outp)
{
  int b=blockIdx.y, i=blockIdx.x, t=threadIdx.x;
  __shared__ float sd[32]; __shared__ int snb[10];
  if(t<30) sd[t]=dirn[((size_t)(b*Vb+i)*10)*3+t];
  if(t<10) snb[t]=nbidx[(size_t)(b*Vb+i)*10+t];
  __syncthreads();
  float acc=feat[(size_t)(b*Vb+i)*NC+t];
  const float* fb=feat+(size_t)b*Vb*NC;
  for(int s=0;s<SUPN;s++){
    int col=s*C+t;
    float w0=cnd[col], w1c=cnd[ncol+col], w2c=cnd[2*ncol+col];
    float m=-INFINITY;
    #pragma unroll
    for(int n=0;n<10;n++){
      float d=sd[3*n]*w0+sd[3*n+1]*w1c+sd[3*n+2]*w2c;
      float th=fast_silu(d);
      float sup=fb[(size_t)snb[n]*NC + (C+col)];
      m=fmaxf(m, th*sup);
    }
    acc+=m;
  }
  outp[(size_t)(b*Vb+i)*C+t]=acc;
}

// ---------------- BN stats ----------------
__global__ void stats_k(const float* __restrict__ xin, int chunk, int C, float* __restrict__ sums)
{
  int t=threadIdx.x;
  size_t r0=(size_t)blockIdx.x*chunk;
  float s=0.0f,s2=0.0f;
  for(int r=0;r<chunk;r++){ float v=xin[(r0+r)*C+t]; s+=v; s2+=v*v; }
  atomicAdd(&sums[t],s); atomicAdd(&sums[C+t],s2);
}

// ---------------- BN apply + silu ----------------
__global__ void bn_silu_k(const float* __restrict__ xin, const float* __restrict__ sums,
                          float invM, int C, const float* __restrict__ g, const float* __restrict__ bb,
                          float* __restrict__ y, int nelem)
{
  int gid=blockIdx.x*blockDim.x+threadIdx.x;
  if(gid>=nelem) return;
  int c=gid&(C-1);
  float mean=sums[c]*invM;
  float var=sums[C+c]*invM - mean*mean;
  float v=(xin[gid]-mean)*rsqrtf(var+1e-5f)*g[c]+bb[c];
  y[gid]=fast_silu(v);
}

// ---------------- pool over first-4 of idx10 at perm rows + coord gather ----------------
__global__ void pool_gather_k(const float* __restrict__ fm, int Vsrc, int C,
                              const int* __restrict__ idx10, const int* __restrict__ perm,
                              const float* __restrict__ vsrc,
                              float* __restrict__ fout, float* __restrict__ vout, int Vq)
{
  int b=blockIdx.y, j=blockIdx.x, t=threadIdx.x;
  int r=perm[j];
  const int* id=idx10+((size_t)b*Vsrc+r)*10;
  const float* fb=fm+(size_t)b*Vsrc*C;
  float m=-INFINITY;
  #pragma unroll
  for(int n=0;n<4;n++) m=fmaxf(m, fb[(size_t)id[n]*C+t]);
  fout[(size_t)(b*Vq+j)*C+t]=m;
  if(t<3) vout[((size_t)b*Vq+j)*3+t]=vsrc[((size_t)b*Vsrc+r)*3+t];
}

// ---------------- final concat with upsampling ----------------
__global__ __launch_bounds__(256) void concat_k(
    const float* __restrict__ fm0, const float* __restrict__ fm1,
    const float* __restrict__ fm2, const float* __restrict__ fm3,
    const float* __restrict__ fm4,
    const int* __restrict__ n1, const int* __restrict__ n2,
    float* __restrict__ outp)
{
  int b=blockIdx.y, i=blockIdx.x, t=threadIdx.x;
  size_t obase=((size_t)b*V0+i)*1280;
  int j1=n1[b*V0+i], j2=n2[b*V0+i];
  if(t<128){
    outp[obase+t]      = fm0[(size_t)(b*V0+i)*128+t];
    outp[obase+128+t]  = fm1[(size_t)(b*V0+i)*128+t];
  }
  outp[obase+256+t] = fm2[((size_t)b*V1N+j1)*256+t];
  outp[obase+512+t] = fm3[((size_t)b*V1N+j1)*256+t];
  outp[obase+768+t]     = fm4[((size_t)b*V2N+j2)*512+t];
  outp[obase+768+256+t] = fm4[((size_t)b*V2N+j2)*512+256+t];
}

extern "C" void kernel_launch(void* const* d_in, const int* in_sizes, int n_in,
                              void* d_out, int out_size, void* d_ws, size_t ws_size,
                              hipStream_t stream) {
  const float* x   =(const float*)d_in[0];
  const float* d0  =(const float*)d_in[1];
  const float* w1  =(const float*)d_in[2];
  const float* b1  =(const float*)d_in[3];
  const float* dir1=(const float*)d_in[4];
  const float* g1  =(const float*)d_in[5];
  const float* bb1 =(const float*)d_in[6];
  const float* w2  =(const float*)d_in[7];
  const float* b2  =(const float*)d_in[8];
  const float* dir2=(const float*)d_in[9];
  const float* g2  =(const float*)d_in[10];
  const float* bb2 =(const float*)d_in[11];
  const float* w3  =(const float*)d_in[12];
  const float* b3  =(const float*)d_in[13];
  const float* dir3=(const float*)d_in[14];
  const float* g3  =(const float*)d_in[15];
  const float* bb3 =(const float*)d_in[16];
  const float* w4  =(const float*)d_in[17];
  const float* b4  =(const float*)d_in[18];
  const float* dir4=(const float*)d_in[19];
  const int* perm1 =(const int*)d_in[20];
  const int* perm2 =(const int*)d_in[21];
  float* out=(float*)d_out;

  float* w=(float*)d_ws;
  size_t off=0;
  auto alloc=[&](size_t n){ float* p=w+off; off+=n; return p; };
  float* cn0 =alloc(2688);
  float* cn1 =alloc(2688);
  float* cn2 =alloc(5376);
  float* cn3 =alloc(5376);
  float* cn4 =alloc(10752);
  float* dirnx =alloc((size_t)BNUM*V0*30);
  float* dirnv1=alloc((size_t)BNUM*V1N*30);
  float* dirnv2=alloc((size_t)BNUM*V2N*30);
  float* fm0 =alloc((size_t)BNUM*V0*128);
  float* feat=alloc((size_t)BNUM*V0*1024);
  float* fm1r=alloc((size_t)BNUM*V0*128);
  float* fm1 =alloc((size_t)BNUM*V0*128);
  float* f1  =alloc((size_t)BNUM*V1N*128);
  float* v1  =alloc((size_t)BNUM*V1N*3);
  float* fm2r=alloc((size_t)BNUM*V1N*256);
  float* fm2 =alloc((size_t)BNUM*V1N*256);
  float* fm3r=alloc((size_t)BNUM*V1N*256);
  float* fm3 =alloc((size_t)BNUM*V1N*256);
  float* f2  =alloc((size_t)BNUM*V2N*256);
  float* v2  =alloc((size_t)BNUM*V2N*3);
  float* fm4 =alloc((size_t)BNUM*V2N*512);
  float* stats=alloc(1280);
  int* idx10x =(int*)alloc((size_t)BNUM*V0*10);
  int* idx10v1=(int*)alloc((size_t)BNUM*V1N*10);
  int* idx10v2=(int*)alloc((size_t)BNUM*V2N*10);
  int* n1i =(int*)alloc((size_t)BNUM*V0);
  int* n2i =(int*)alloc((size_t)BNUM*V0);

  hipMemsetAsync(stats, 0, 1280*sizeof(float), stream);
  colnorm_all_k<<<dim3(35),256,0,stream>>>(d0,dir1,dir2,dir3,dir4,cn0,cn1,cn2,cn3,cn4);

  // knn10 on x (+dirn)
  knn10_k<V0><<<dim3(V0/4,BNUM),256,0,stream>>>(x, idx10x, dirnx);
  conv_surf_k<<<dim3(V0,BNUM),128,0,stream>>>(dirnx, cn0, fm0);

  // layer 1
  gemm_bias_k<<<dim3(1024/64,(BNUM*V0)/128),256,0,stream>>>(fm0, w1, b1, feat, BNUM*V0, 1024, 128);
  conv_agg_k<<<dim3(V0,BNUM),128,0,stream>>>(feat, V0, 128, 1024, dirnx, idx10x, cn1, 896, fm1r);
  stats_k<<<dim3((BNUM*V0)/64),128,0,stream>>>(fm1r, 64, 128, stats);
  bn_silu_k<<<dim3((BNUM*V0*128)/256),256,0,stream>>>(fm1r, stats, 1.0f/(BNUM*V0), 128, g1, bb1, fm1, BNUM*V0*128);

  // pool (first-4 of idx10x at perm1) + v1 gather
  pool_gather_k<<<dim3(V1N,BNUM),128,0,stream>>>(fm1, V0, 128, idx10x, perm1, x, f1, v1, V1N);

  // knn10 on v1
  knn10_k<V1N><<<dim3(V1N/4,BNUM),256,0,stream>>>(v1, idx10v1, dirnv1);

  // layer 2
  gemm_bias_k<<<dim3(2048/64,(BNUM*V1N)/128),256,0,stream>>>(f1, w2, b2, feat, BNUM*V1N, 2048, 128);
  conv_agg_k<<<dim3(V1N,BNUM),256,0,stream>>>(feat, V1N, 256, 2048, dirnv1, idx10v1, cn2, 1792, fm2r);
  stats_k<<<dim3((BNUM*V1N)/64),256,0,stream>>>(fm2r, 64, 256, stats+256);
  bn_silu_k<<<dim3((BNUM*V1N*256)/256),256,0,stream>>>(fm2r, stats+256, 1.0f/(BNUM*V1N), 256, g2, bb2, fm2, BNUM*V1N*256);

  // layer 3
  gemm_bias_k<<<dim3(2048/64,(BNUM*V1N)/128),256,0,stream>>>(fm2, w3, b3, feat, BNUM*V1N, 2048, 256);
  conv_agg_k<<<dim3(V1N,BNUM),256,0,stream>>>(feat, V1N, 256, 2048, dirnv1, idx10v1, cn3, 1792, fm3r);
  stats_k<<<dim3((BNUM*V1N)/64),256,0,stream>>>(fm3r, 64, 256, stats+768);
  bn_silu_k<<<dim3((BNUM*V1N*256)/256),256,0,stream>>>(fm3r, stats+768, 1.0f/(BNUM*V1N), 256, g3, bb3, fm3, BNUM*V1N*256);

  // pool (first-4 of idx10v1 at perm2) + v2 gather
  pool_gather_k<<<dim3(V2N,BNUM),256,0,stream>>>(fm3, V1N, 256, idx10v1, perm2, v1, f2, v2, V2N);

  // knn10 on v2
  knn10_k<V2N><<<dim3(V2N/4,BNUM),256,0,stream>>>(v2, idx10v2, dirnv2);

  // layer 4 (no bn/silu)
  gemm_bias_k<<<dim3(4096/64,(BNUM*V2N)/128),256,0,stream>>>(f2, w4, b4, feat, BNUM*V2N, 4096, 256);
  conv_agg_k<<<dim3(V2N,BNUM),512,0,stream>>>(feat, V2N, 512, 4096, dirnv2, idx10v2, cn4, 3584, fm4);

  // nearest upsample indices
  nearest_k<V1N><<<dim3(V0/4,BNUM),256,0,stream>>>(v1, x, n1i);
  nearest_k<V2N><<<dim3(V0/4,BNUM),256,0,stream>>>(v2, x, n2i);

  // final concat
  concat_k<<<dim3(V0,BNUM),256,0,stream>>>(fm0, fm1, fm2, fm3, fm4, n1i, n2i, out);
}

// Round 3
// 743.889 us; speedup vs baseline: 1.0631x; 1.0631x over previous
//
#include <hip/hip_runtime.h>
#include <math.h>
#include <float.h>
#include <limits.h>

#define BNUM 2
#define V0 4096
#define V1N 1024
#define V2N 256
#define SUPN 7

typedef float float4v __attribute__((ext_vector_type(4)));

__device__ __forceinline__ float fast_silu(float x){
  return __fdividef(x, 1.0f + __expf(-x));
}

// ---------------- fused column-normalize for all 5 direction banks ----------------
__global__ void colnorm_all_k(const float* __restrict__ d0, const float* __restrict__ dir1,
                              const float* __restrict__ dir2, const float* __restrict__ dir3,
                              const float* __restrict__ dir4,
                              float* __restrict__ cn0, float* __restrict__ cn1,
                              float* __restrict__ cn2, float* __restrict__ cn3,
                              float* __restrict__ cn4){
  int c = blockIdx.x*256 + threadIdx.x;
  const float* s; float* o; int nc;
  if(c < 896){ s=d0; o=cn0; nc=896; }
  else if((c-=896) < 896){ s=dir1; o=cn1; nc=896; }
  else if((c-=896) < 1792){ s=dir2; o=cn2; nc=1792; }
  else if((c-=1792) < 1792){ s=dir3; o=cn3; nc=1792; }
  else { c-=1792; if(c>=3584) return; s=dir4; o=cn4; nc=3584; }
  float a=s[c], b=s[nc+c], e=s[2*nc+c];
  float n=sqrtf(a*a+b*b+e*e); n=fmaxf(n,1e-12f);
  o[c]=a/n; o[nc+c]=b/n; o[2*nc+c]=e/n;
}

// ---------------- self-KNN (k=10, skip self): LDS-staged points, one wave/query ----
// Block = 512 threads = 8 query-waves sharing one LDS staging of all VC points.
template<int VC>
__global__ __launch_bounds__(512) void knn10_k(const float* __restrict__ pts,
    int* __restrict__ out_idx, float* __restrict__ out_dirn)
{
  constexpr int CHUNK = VC/64;
  constexpr int TOT = 11;
  __shared__ float sp[3*VC];
  int t = threadIdx.x;
  int lane = t & 63;
  int wv   = t >> 6;
  int b = blockIdx.y;
  int j = blockIdx.x*8 + wv;
  const float* pb = pts + (size_t)b*VC*3;
  // cooperative stage: 3*VC floats via float4
  for(int i=t; i<3*VC/4; i+=512)
    ((float4v*)sp)[i] = ((const float4v*)pb)[i];
  __syncthreads();
  float qx=pb[3*j], qy=pb[3*j+1], qz=pb[3*j+2];   // wave-uniform -> scalar loads
  float qs=qx*qx+qy*qy+qz*qz;

  float t0=FLT_MAX,t1=FLT_MAX,t2=FLT_MAX,t3=FLT_MAX;
  int   i0=INT_MAX,i1=INT_MAX,i2=INT_MAX,i3=INT_MAX;
  #pragma unroll 4
  for(int c=0;c<CHUNK;c++){
    int i = c*64 + lane;
    float cx=sp[3*i], cy=sp[3*i+1], cz=sp[3*i+2];
    float cs=cx*cx+cy*cy+cz*cz;
    float dt=qx*cx+qy*cy+qz*cz;
    float d=qs+cs-2.0f*dt;
    if(d<t3){
      if(d<t2){ t3=t2;i3=i2;
        if(d<t1){ t2=t1;i2=i1;
          if(d<t0){ t1=t0;i1=i0; t0=d;i0=i; }
          else    { t1=d;i1=i; }
        } else   { t2=d;i2=i; }
      } else     { t3=d;i3=i; }
    }
  }
  // extraction: enumerate pool in (d,idx)-ascending order
  float pd=-FLT_MAX; int pi=-1;
  int wi=0;
  for(int sel=0; sel<TOT; ++sel){
    bool g0=(t0>pd)||(t0==pd&&i0>pi);
    bool g1=(t1>pd)||(t1==pd&&i1>pi);
    bool g2=(t2>pd)||(t2==pd&&i2>pi);
    bool g3=(t3>pd)||(t3==pd&&i3>pi);
    float cd = g0?t0:(g1?t1:(g2?t2:(g3?t3:FLT_MAX)));
    int   ci = g0?i0:(g1?i1:(g2?i2:(g3?i3:INT_MAX)));
    #pragma unroll
    for(int s=32;s;s>>=1){
      float od=__shfl_xor(cd,s);
      int   oi=__shfl_xor(ci,s);
      if(od<cd || (od==cd && oi<ci)){cd=od;ci=oi;}
    }
    if(lane==sel) wi=ci;
    pd=cd; pi=ci;
  }
  // exactness guard: if my 4th-best was selected, my unseen 5th might belong
  bool bad = (t3<pd) || (t3==pd && i3<=pi);
  if(__any(bad)){
    pd=-FLT_MAX; pi=-1;
    for(int sel=0; sel<TOT; ++sel){
      float cd=FLT_MAX; int ci=INT_MAX;
      for(int c=0;c<CHUNK;c++){
        int i=c*64+lane;
        float cx=sp[3*i], cy=sp[3*i+1], cz=sp[3*i+2];
        float cs=cx*cx+cy*cy+cz*cz;
        float dt=qx*cx+qy*cy+qz*cz;
        float d=qs+cs-2.0f*dt;
        bool ok = ((d>pd)||(d==pd&&i>pi)) && ((d<cd)||(d==cd&&i<ci));
        if(ok){cd=d;ci=i;}
      }
      #pragma unroll
      for(int s=32;s;s>>=1){
        float od=__shfl_xor(cd,s);
        int   oi=__shfl_xor(ci,s);
        if(od<cd || (od==cd && oi<ci)){cd=od;ci=oi;}
      }
      if(lane==sel) wi=ci;
      pd=cd; pi=ci;
    }
  }
  if(lane>=1 && lane<TOT){
    size_t obase=((size_t)b*VC+j)*10 + (lane-1);
    out_idx[obase]=wi;
    float dx=sp[3*wi]-qx, dy=sp[3*wi+1]-qy, dz=sp[3*wi+2]-qz;
    float n=sqrtf(dx*dx+dy*dy+dz*dz); n=fmaxf(n,1e-12f);
    out_dirn[obase*3]=dx/n; out_dirn[obase*3+1]=dy/n; out_dirn[obase*3+2]=dz/n;
  }
}

// ---------------- nearest (argmin, ties -> lower index): LDS-staged candidates ----
template<int VC>
__global__ __launch_bounds__(512) void nearest_k(
    const float* __restrict__ src,  // (B, VC, 3) candidates
    const float* __restrict__ tgt,  // (B, V0, 3) queries
    int* __restrict__ outp)         // (B, V0)
{
  constexpr int CHUNK = VC/64;
  __shared__ float sp[3*VC];
  int t=threadIdx.x;
  int lane=t&63, wv=t>>6;
  int b=blockIdx.y; int j=blockIdx.x*8+wv;
  const float* cb=src+(size_t)b*VC*3;
  for(int i=t; i<3*VC/4; i+=512)
    ((float4v*)sp)[i] = ((const float4v*)cb)[i];
  __syncthreads();
  const float* qb=tgt+(size_t)b*V0*3;
  float qx=qb[3*j],qy=qb[3*j+1],qz=qb[3*j+2];
  float qs=qx*qx+qy*qy+qz*qz;
  float bd=FLT_MAX; int bi=INT_MAX;
  #pragma unroll 4
  for(int c=0;c<CHUNK;c++){
    int i=c*64+lane;
    float cx=sp[3*i],cy=sp[3*i+1],cz=sp[3*i+2];
    float cs=cx*cx+cy*cy+cz*cz;
    float dt=qx*cx+qy*cy+qz*cz;
    float d=qs+cs-2.0f*dt;
    if(d<bd || (d==bd && i<bi)){bd=d;bi=i;}
  }
  #pragma unroll
  for(int s=32;s;s>>=1){
    float od=__shfl_xor(bd,s);
    int   oi=__shfl_xor(bi,s);
    if(od<bd || (od==bd && oi<bi)){bd=od;bi=oi;}
  }
  if(lane==0) outp[(size_t)b*V0+j]=bi;
}

// ---------------- conv_surface + outer silu -> fm0 (C=128) ----------------
__global__ __launch_bounds__(128) void conv_surf_k(
    const float* __restrict__ dirn, const float* __restrict__ cnd,
    float* __restrict__ fm0)
{
  int b=blockIdx.y, i=blockIdx.x, t=threadIdx.x;
  __shared__ float sd[32];
  if(t<30) sd[t]=dirn[((size_t)(b*V0+i)*10)*3+t];
  __syncthreads();
  float acc=0.0f;
  for(int s=0;s<SUPN;s++){
    int col=s*128+t;
    float w0=cnd[col], w1c=cnd[896+col], w2c=cnd[1792+col];
    float m=-INFINITY;
    #pragma unroll
    for(int n=0;n<10;n++){
      float d=sd[3*n]*w0+sd[3*n+1]*w1c+sd[3*n+2]*w2c;
      m=fmaxf(m, fast_silu(d));
    }
    acc+=m;
  }
  fm0[(size_t)(b*V0+i)*128+t]=fast_silu(acc);
}

// ---------------- GEMM: C[M,N] = A[M,K] @ W[K,N] + bias[N] ----------------
// 128x128 tile, BK=16, 256 threads, 8x8 per thread as split 4+4 fragments.
// Requires M%128==0, N%128==0, K%16==0 (all shapes satisfy).
__global__ __launch_bounds__(256) void gemm_bias_k(
    const float* __restrict__ A, const float* __restrict__ W,
    const float* __restrict__ bias, float* __restrict__ C,
    int M, int N, int K)
{
  __shared__ float As[16][132];   // [k][m]
  __shared__ float Bs[16][132];   // [k][n]
  int t=threadIdx.x;
  int tx=t&15, ty=t>>4;           // tx: n-quad, ty: m-quad
  int bm=blockIdx.y*128, bn=blockIdx.x*128;
  float4v acc[2][2][4];           // [mh][nh][mi]
  #pragma unroll
  for(int a=0;a<2;a++)
    #pragma unroll
    for(int bidx=0;bidx<2;bidx++)
      #pragma unroll
      for(int m=0;m<4;m++) acc[a][bidx][m]=(float4v)(0.0f);
  int arow=t>>2, akk=(t&3)*4;     // A: 64 rows x (4 k-quads)
  int brow=t>>4, bcol=(t&15)*4;   // B: 16 k-rows x (16 n-quads)
  for(int k0=0;k0<K;k0+=16){
    float4v a0=*(const float4v*)&A[(size_t)(bm+arow)*K    + k0+akk];
    float4v a1=*(const float4v*)&A[(size_t)(bm+64+arow)*K + k0+akk];
    float4v b0=*(const float4v*)&W[(size_t)(k0+brow)*N + bn+bcol];
    float4v b1=*(const float4v*)&W[(size_t)(k0+brow)*N + bn+64+bcol];
    __syncthreads();
    #pragma unroll
    for(int u=0;u<4;u++){ As[akk+u][arow]=a0[u]; As[akk+u][64+arow]=a1[u]; }
    *(float4v*)&Bs[brow][bcol]=b0;
    *(float4v*)&Bs[brow][64+bcol]=b1;
    __syncthreads();
    #pragma unroll
    for(int kk=0;kk<16;kk++){
      float4v alo=*(const float4v*)&As[kk][ty*4];
      float4v ahi=*(const float4v*)&As[kk][64+ty*4];
      float4v blo=*(const float4v*)&Bs[kk][tx*4];
      float4v bhi=*(const float4v*)&Bs[kk][64+tx*4];
      #pragma unroll
      for(int mi=0;mi<4;mi++){
        acc[0][0][mi] += alo[mi]*blo;
        acc[0][1][mi] += alo[mi]*bhi;
        acc[1][0][mi] += ahi[mi]*blo;
        acc[1][1][mi] += ahi[mi]*bhi;
      }
    }
  }
  float4v bl=*(const float4v*)&bias[bn+tx*4];
  float4v bh=*(const float4v*)&bias[bn+64+tx*4];
  #pragma unroll
  for(int mh=0;mh<2;mh++)
    #pragma unroll
    for(int mi=0;mi<4;mi++){
      size_t row=(size_t)(bm+mh*64+ty*4+mi);
      *(float4v*)&C[row*N + bn+tx*4]    = acc[mh][0][mi]+bl;
      *(float4v*)&C[row*N + bn+64+tx*4] = acc[mh][1][mi]+bh;
    }
}

// ---------------- conv_layer aggregate: out = center + sum_s max_n theta*support ----
__global__ void conv_agg_k(
    const float* __restrict__ feat, int Vb, int C, int NC,
    const float* __restrict__ dirn, const int* __restrict__ nbidx,
    const float* __restrict__ cnd, int ncol,
    float* __restrict__ outp)
{
  int b=blockIdx.y, i=blockIdx.x, t=threadIdx.x;
  __shared__ float sd[32]; __shared__ int snb[10];
  if(t<30) sd[t]=dirn[((size_t)(b*Vb+i)*10)*3+t];
  if(t<10) snb[t]=nbidx[(size_t)(b*Vb+i)*10+t];
  __syncthreads();
  float acc=feat[(size_t)(b*Vb+i)*NC+t];
  const float* fb=feat+(size_t)b*Vb*NC;
  for(int s=0;s<SUPN;s++){
    int col=s*C+t;
    float w0=cnd[col], w1c=cnd[ncol+col], w2c=cnd[2*ncol+col];
    float m=-INFINITY;
    #pragma unroll
    for(int n=0;n<10;n++){
      float d=sd[3*n]*w0+sd[3*n+1]*w1c+sd[3*n+2]*w2c;
      float th=fast_silu(d);
      float sup=fb[(size_t)snb[n]*NC + (C+col)];
      m=fmaxf(m, th*sup);
    }
    acc+=m;
  }
  outp[(size_t)(b*Vb+i)*C+t]=acc;
}

// ---------------- BN stats ----------------
__global__ void stats_k(const float* __restrict__ xin, int chunk, int C, float* __restrict__ sums)
{
  int t=threadIdx.x;
  size_t r0=(size_t)blockIdx.x*chunk;
  float s=0.0f,s2=0.0f;
  for(int r=0;r<chunk;r++){ float v=xin[(r0+r)*C+t]; s+=v; s2+=v*v; }
  atomicAdd(&sums[t],s); atomicAdd(&sums[C+t],s2);
}

// ---------------- BN apply + silu ----------------
__global__ void bn_silu_k(const float* __restrict__ xin, const float* __restrict__ sums,
                          float invM, int C, const float* __restrict__ g, const float* __restrict__ bb,
                          float* __restrict__ y, int nelem)
{
  int gid=blockIdx.x*blockDim.x+threadIdx.x;
  if(gid>=nelem) return;
  int c=gid&(C-1);
  float mean=sums[c]*invM;
  float var=sums[C+c]*invM - mean*mean;
  float v=(xin[gid]-mean)*rsqrtf(var+1e-5f)*g[c]+bb[c];
  y[gid]=fast_silu(v);
}

// ---------------- pool over first-4 of idx10 at perm rows + coord gather ----------------
__global__ void pool_gather_k(const float* __restrict__ fm, int Vsrc, int C,
                              const int* __restrict__ idx10, const int* __restrict__ perm,
                              const float* __restrict__ vsrc,
                              float* __restrict__ fout, float* __restrict__ vout, int Vq)
{
  int b=blockIdx.y, j=blockIdx.x, t=threadIdx.x;
  int r=perm[j];
  const int* id=idx10+((size_t)b*Vsrc+r)*10;
  const float* fb=fm+(size_t)b*Vsrc*C;
  float m=-INFINITY;
  #pragma unroll
  for(int n=0;n<4;n++) m=fmaxf(m, fb[(size_t)id[n]*C+t]);
  fout[(size_t)(b*Vq+j)*C+t]=m;
  if(t<3) vout[((size_t)b*Vq+j)*3+t]=vsrc[((size_t)b*Vsrc+r)*3+t];
}

// ---------------- final concat with upsampling ----------------
__global__ __launch_bounds__(256) void concat_k(
    const float* __restrict__ fm0, const float* __restrict__ fm1,
    const float* __restrict__ fm2, const float* __restrict__ fm3,
    const float* __restrict__ fm4,
    const int* __restrict__ n1, const int* __restrict__ n2,
    float* __restrict__ outp)
{
  int b=blockIdx.y, i=blockIdx.x, t=threadIdx.x;
  size_t obase=((size_t)b*V0+i)*1280;
  int j1=n1[b*V0+i], j2=n2[b*V0+i];
  if(t<128){
    outp[obase+t]      = fm0[(size_t)(b*V0+i)*128+t];
    outp[obase+128+t]  = fm1[(size_t)(b*V0+i)*128+t];
  }
  outp[obase+256+t] = fm2[((size_t)b*V1N+j1)*256+t];
  outp[obase+512+t] = fm3[((size_t)b*V1N+j1)*256+t];
  outp[obase+768+t]     = fm4[((size_t)b*V2N+j2)*512+t];
  outp[obase+768+256+t] = fm4[((size_t)b*V2N+j2)*512+256+t];
}

extern "C" void kernel_launch(void* const* d_in, const int* in_sizes, int n_in,
                              void* d_out, int out_size, void* d_ws, size_t ws_size,
                              hipStream_t stream) {
  const float* x   =(const float*)d_in[0];
  const float* d0  =(const float*)d_in[1];
  const float* w1  =(const float*)d_in[2];
  const float* b1  =(const float*)d_in[3];
  const float* dir1=(const float*)d_in[4];
  const float* g1  =(const float*)d_in[5];
  const float* bb1 =(const float*)d_in[6];
  const float* w2  =(const float*)d_in[7];
  const float* b2  =(const float*)d_in[8];
  const float* dir2=(const float*)d_in[9];
  const float* g2  =(const float*)d_in[10];
  const float* bb2 =(const float*)d_in[11];
  const float* w3  =(const float*)d_in[12];
  const float* b3  =(const float*)d_in[13];
  const float* dir3=(const float*)d_in[14];
  const float* g3  =(const float*)d_in[15];
  const float* bb3 =(const float*)d_in[16];
  const float* w4  =(const float*)d_in[17];
  const float* b4  =(const float*)d_in[18];
  const float* dir4=(const float*)d_in[19];
  const int* perm1 =(const int*)d_in[20];
  const int* perm2 =(const int*)d_in[21];
  float* out=(float*)d_out;

  float* w=(float*)d_ws;
  size_t off=0;
  auto alloc=[&](size_t n){ float* p=w+off; off+=n; return p; };
  float* cn0 =alloc(2688);
  float* cn1 =alloc(2688);
  float* cn2 =alloc(5376);
  float* cn3 =alloc(5376);
  float* cn4 =alloc(10752);
  float* dirnx =alloc((size_t)BNUM*V0*30);
  float* dirnv1=alloc((size_t)BNUM*V1N*30);
  float* dirnv2=alloc((size_t)BNUM*V2N*30);
  float* fm0 =alloc((size_t)BNUM*V0*128);
  float* feat=alloc((size_t)BNUM*V0*1024);
  float* fm1r=alloc((size_t)BNUM*V0*128);
  float* fm1 =alloc((size_t)BNUM*V0*128);
  float* f1  =alloc((size_t)BNUM*V1N*128);
  float* v1  =alloc((size_t)BNUM*V1N*3);
  float* fm2r=alloc((size_t)BNUM*V1N*256);
  float* fm2 =alloc((size_t)BNUM*V1N*256);
  float* fm3r=alloc((size_t)BNUM*V1N*256);
  float* fm3 =alloc((size_t)BNUM*V1N*256);
  float* f2  =alloc((size_t)BNUM*V2N*256);
  float* v2  =alloc((size_t)BNUM*V2N*3);
  float* fm4 =alloc((size_t)BNUM*V2N*512);
  float* stats=alloc(1280);
  int* idx10x =(int*)alloc((size_t)BNUM*V0*10);
  int* idx10v1=(int*)alloc((size_t)BNUM*V1N*10);
  int* idx10v2=(int*)alloc((size_t)BNUM*V2N*10);
  int* n1i =(int*)alloc((size_t)BNUM*V0);
  int* n2i =(int*)alloc((size_t)BNUM*V0);

  hipMemsetAsync(stats, 0, 1280*sizeof(float), stream);
  colnorm_all_k<<<dim3(35),256,0,stream>>>(d0,dir1,dir2,dir3,dir4,cn0,cn1,cn2,cn3,cn4);

  // knn10 on x (+dirn)
  knn10_k<V0><<<dim3(V0/8,BNUM),512,0,stream>>>(x, idx10x, dirnx);
  conv_surf_k<<<dim3(V0,BNUM),128,0,stream>>>(dirnx, cn0, fm0);

  // layer 1
  gemm_bias_k<<<dim3(1024/128,(BNUM*V0)/128),256,0,stream>>>(fm0, w1, b1, feat, BNUM*V0, 1024, 128);
  conv_agg_k<<<dim3(V0,BNUM),128,0,stream>>>(feat, V0, 128, 1024, dirnx, idx10x, cn1, 896, fm1r);
  stats_k<<<dim3((BNUM*V0)/64),128,0,stream>>>(fm1r, 64, 128, stats);
  bn_silu_k<<<dim3((BNUM*V0*128)/256),256,0,stream>>>(fm1r, stats, 1.0f/(BNUM*V0), 128, g1, bb1, fm1, BNUM*V0*128);

  // pool (first-4 of idx10x at perm1) + v1 gather
  pool_gather_k<<<dim3(V1N,BNUM),128,0,stream>>>(fm1, V0, 128, idx10x, perm1, x, f1, v1, V1N);

  // knn10 on v1
  knn10_k<V1N><<<dim3(V1N/8,BNUM),512,0,stream>>>(v1, idx10v1, dirnv1);

  // layer 2
  gemm_bias_k<<<dim3(2048/128,(BNUM*V1N)/128),256,0,stream>>>(f1, w2, b2, feat, BNUM*V1N, 2048, 128);
  conv_agg_k<<<dim3(V1N,BNUM),256,0,stream>>>(feat, V1N, 256, 2048, dirnv1, idx10v1, cn2, 1792, fm2r);
  stats_k<<<dim3((BNUM*V1N)/64),256,0,stream>>>(fm2r, 64, 256, stats+256);
  bn_silu_k<<<dim3((BNUM*V1N*256)/256),256,0,stream>>>(fm2r, stats+256, 1.0f/(BNUM*V1N), 256, g2, bb2, fm2, BNUM*V1N*256);

  // layer 3
  gemm_bias_k<<<dim3(2048/128,(BNUM*V1N)/128),256,0,stream>>>(fm2, w3, b3, feat, BNUM*V1N, 2048, 256);
  conv_agg_k<<<dim3(V1N,BNUM),256,0,stream>>>(feat, V1N, 256, 2048, dirnv1, idx10v1, cn3, 1792, fm3r);
  stats_k<<<dim3((BNUM*V1N)/64),256,0,stream>>>(fm3r, 64, 256, stats+768);
  bn_silu_k<<<dim3((BNUM*V1N*256)/256),256,0,stream>>>(fm3r, stats+768, 1.0f/(BNUM*V1N), 256, g3, bb3, fm3, BNUM*V1N*256);

  // pool (first-4 of idx10v1 at perm2) + v2 gather
  pool_gather_k<<<dim3(V2N,BNUM),256,0,stream>>>(fm3, V1N, 256, idx10v1, perm2, v1, f2, v2, V2N);

  // knn10 on v2
  knn10_k<V2N><<<dim3(V2N/8,BNUM),512,0,stream>>>(v2, idx10v2, dirnv2);

  // layer 4 (no bn/silu)
  gemm_bias_k<<<dim3(4096/128,(BNUM*V2N)/128),256,0,stream>>>(f2, w4, b4, feat, BNUM*V2N, 4096, 256);
  conv_agg_k<<<dim3(V2N,BNUM),512,0,stream>>>(feat, V2N, 512, 4096, dirnv2, idx10v2, cn4, 3584, fm4);

  // nearest upsample indices
  nearest_k<V1N><<<dim3(V0/8,BNUM),512,0,stream>>>(v1, x, n1i);
  nearest_k<V2N><<<dim3(V0/8,BNUM),512,0,stream>>>(v2, x, n2i);

  // final concat
  concat_k<<<dim3(V0,BNUM),256,0,stream>>>(fm0, fm1, fm2, fm3, fm4, n1i, n2i, out);
}

// Round 4
// 665.868 us; speedup vs baseline: 1.1877x; 1.1172x over previous
//
#include <hip/hip_runtime.h>
#include <math.h>
#include <float.h>
#include <limits.h>

#define BNUM 2
#define V0 4096
#define V1N 1024
#define V2N 256
#define SUPN 7

typedef float float4v __attribute__((ext_vector_type(4)));
typedef float float2v __attribute__((ext_vector_type(2)));

__device__ __forceinline__ float fast_silu(float x){
  return __fdividef(x, 1.0f + __expf(-x));
}

// exact monotone float->uint transform: a<b (float) <=> key(a)<key(b) (uint)
__device__ __forceinline__ unsigned int fkey(float f){
  unsigned int u = __float_as_uint(f);
  int m = ((int)u) >> 31;
  return u ^ (unsigned int)(m | 0x80000000);
}

// ---------------- fused column-normalize + stats zero ----------------
__global__ void colnorm_all_k(const float* __restrict__ d0, const float* __restrict__ dir1,
                              const float* __restrict__ dir2, const float* __restrict__ dir3,
                              const float* __restrict__ dir4,
                              float* __restrict__ cn0, float* __restrict__ cn1,
                              float* __restrict__ cn2, float* __restrict__ cn3,
                              float* __restrict__ cn4, float* __restrict__ stats){
  int c = blockIdx.x*256 + threadIdx.x;
  if(c < 1280) stats[c] = 0.0f;
  const float* s; float* o; int nc;
  if(c < 896){ s=d0; o=cn0; nc=896; }
  else if((c-=896) < 896){ s=dir1; o=cn1; nc=896; }
  else if((c-=896) < 1792){ s=dir2; o=cn2; nc=1792; }
  else if((c-=1792) < 1792){ s=dir3; o=cn3; nc=1792; }
  else { c-=1792; if(c>=3584) return; s=dir4; o=cn4; nc=3584; }
  float a=s[c], b=s[nc+c], e=s[2*nc+c];
  float n=sqrtf(a*a+b*b+e*e); n=fmaxf(n,1e-12f);
  o[c]=a/n; o[nc+c]=b/n; o[2*nc+c]=e/n;
}

// ---------------- self-KNN (k=10, skip self) ----------------
// LDS holds (x,y,z,|c|^2) float4 per point. One wave per query.
// Per-lane branchless top-4 on (key,idx); 11 shuffle-extraction rounds; exact fallback.
template<int VC, int THREADS>
__global__ __launch_bounds__(THREADS) void knn10_k(const float* __restrict__ pts,
    int* __restrict__ out_idx, float* __restrict__ out_dirn)
{
  constexpr int CHUNK = VC/64;
  constexpr int QPB = THREADS/64;
  constexpr int TOT = 11;
  __shared__ float4v sp4[VC];
  int t = threadIdx.x;
  int lane = t & 63;
  int wv   = t >> 6;
  int b = blockIdx.y;
  int j = blockIdx.x*QPB + wv;
  const float* pb = pts + (size_t)b*VC*3;
  for(int i=t; i<VC; i+=THREADS){
    float x=pb[3*i], y=pb[3*i+1], z=pb[3*i+2];
    float4v v; v[0]=x; v[1]=y; v[2]=z; v[3]=x*x+y*y+z*z;
    sp4[i]=v;
  }
  __syncthreads();
  float qx=pb[3*j], qy=pb[3*j+1], qz=pb[3*j+2];
  float qs=qx*qx+qy*qy+qz*qz;

  unsigned int k0=0xFFFFFFFFu,k1=0xFFFFFFFFu,k2=0xFFFFFFFFu,k3=0xFFFFFFFFu;
  int i0=INT_MAX,i1=INT_MAX,i2=INT_MAX,i3=INT_MAX;
  #pragma unroll 4
  for(int c=0;c<CHUNK;c++){
    int i = c*64 + lane;
    float4v p = sp4[i];
    float dot = qx*p[0]+qy*p[1]+qz*p[2];
    float d = fmaf(-2.0f, dot, p[3]+qs);
    unsigned int k = fkey(d);
    // branchless sorted insert (strict <; stream idx increasing handles key ties)
    bool c3 = k < k3;
    k3 = c3 ? k : k3;  i3 = c3 ? i : i3;
    bool c2 = k3 < k2;
    unsigned int tk = c2?k3:k2; k3 = c2?k2:k3; k2 = tk;
    int ti = c2?i3:i2; i3 = c2?i2:i3; i2 = ti;
    bool c1 = k2 < k1;
    tk = c1?k2:k1; k2 = c1?k1:k2; k1 = tk;
    ti = c1?i2:i1; i2 = c1?i1:i2; i1 = ti;
    bool c0 = k1 < k0;
    tk = c0?k1:k0; k1 = c0?k0:k1; k0 = tk;
    ti = c0?i1:i0; i1 = c0?i0:i1; i0 = ti;
  }
  // extraction: enumerate (key,idx)-ascending across the wave pool
  unsigned int pk=0u; int pi=-1;
  int wi=0;
  for(int sel=0; sel<TOT; ++sel){
    bool g0=(k0>pk)||(k0==pk&&i0>pi);
    bool g1=(k1>pk)||(k1==pk&&i1>pi);
    bool g2=(k2>pk)||(k2==pk&&i2>pi);
    bool g3=(k3>pk)||(k3==pk&&i3>pi);
    unsigned int ck = g0?k0:(g1?k1:(g2?k2:(g3?k3:0xFFFFFFFFu)));
    int          ci = g0?i0:(g1?i1:(g2?i2:(g3?i3:INT_MAX)));
    #pragma unroll
    for(int s=32;s;s>>=1){
      unsigned int ok=__shfl_xor(ck,s);
      int          oi=__shfl_xor(ci,s);
      if(ok<ck || (ok==ck && oi<ci)){ck=ok;ci=oi;}
    }
    if(lane==sel) wi=ci;
    pk=ck; pi=ci;
  }
  // exactness guard
  bool bad = (k3<pk) || (k3==pk && i3<=pi);
  if(__any(bad)){
    pk=0u; pi=-1;
    for(int sel=0; sel<TOT; ++sel){
      unsigned int ck=0xFFFFFFFFu; int ci=INT_MAX;
      for(int c=0;c<CHUNK;c++){
        int i=c*64+lane;
        float4v p = sp4[i];
        float dot = qx*p[0]+qy*p[1]+qz*p[2];
        float d = fmaf(-2.0f, dot, p[3]+qs);
        unsigned int k = fkey(d);
        bool ok2 = ((k>pk)||(k==pk&&i>pi)) && ((k<ck)||(k==ck&&i<ci));
        if(ok2){ck=k;ci=i;}
      }
      #pragma unroll
      for(int s=32;s;s>>=1){
        unsigned int ok=__shfl_xor(ck,s);
        int          oi=__shfl_xor(ci,s);
        if(ok<ck || (ok==ck && oi<ci)){ck=ok;ci=oi;}
      }
      if(lane==sel) wi=ci;
      pk=ck; pi=ci;
    }
  }
  if(lane>=1 && lane<TOT){
    size_t obase=((size_t)b*VC+j)*10 + (lane-1);
    out_idx[obase]=wi;
    float4v p = sp4[wi];
    float dx=p[0]-qx, dy=p[1]-qy, dz=p[2]-qz;
    float n=sqrtf(dx*dx+dy*dy+dz*dz); n=fmaxf(n,1e-12f);
    out_dirn[obase*3]=dx/n; out_dirn[obase*3+1]=dy/n; out_dirn[obase*3+2]=dz/n;
  }
}

// ---------------- fused nearest for v1 and v2 (argmin, ties -> lower index) ----------
__global__ __launch_bounds__(512) void nearest_both_k(
    const float* __restrict__ v1, const float* __restrict__ v2,
    const float* __restrict__ x,
    int* __restrict__ n1, int* __restrict__ n2)
{
  __shared__ float4v s1[V1N];
  __shared__ float4v s2[V2N];
  int t=threadIdx.x;
  int lane=t&63, wv=t>>6;
  int b=blockIdx.y; int j=blockIdx.x*8+wv;
  const float* c1=v1+(size_t)b*V1N*3;
  const float* c2=v2+(size_t)b*V2N*3;
  for(int i=t;i<V1N;i+=512){
    float xx=c1[3*i],yy=c1[3*i+1],zz=c1[3*i+2];
    float4v v; v[0]=xx;v[1]=yy;v[2]=zz;v[3]=xx*xx+yy*yy+zz*zz; s1[i]=v;
  }
  for(int i=t;i<V2N;i+=512){
    float xx=c2[3*i],yy=c2[3*i+1],zz=c2[3*i+2];
    float4v v; v[0]=xx;v[1]=yy;v[2]=zz;v[3]=xx*xx+yy*yy+zz*zz; s2[i]=v;
  }
  __syncthreads();
  const float* qb=x+(size_t)b*V0*3;
  float qx=qb[3*j],qy=qb[3*j+1],qz=qb[3*j+2];
  float qs=qx*qx+qy*qy+qz*qz;
  // scan v1
  unsigned int bk=0xFFFFFFFFu; int bi=INT_MAX;
  #pragma unroll 4
  for(int c=0;c<V1N/64;c++){
    int i=c*64+lane;
    float4v p=s1[i];
    float dot=qx*p[0]+qy*p[1]+qz*p[2];
    float d=fmaf(-2.0f,dot,p[3]+qs);
    unsigned int k=fkey(d);
    if(k<bk){bk=k;bi=i;}
  }
  #pragma unroll
  for(int s=32;s;s>>=1){
    unsigned int ok=__shfl_xor(bk,s); int oi=__shfl_xor(bi,s);
    if(ok<bk || (ok==bk && oi<bi)){bk=ok;bi=oi;}
  }
  if(lane==0) n1[(size_t)b*V0+j]=bi;
  // scan v2
  bk=0xFFFFFFFFu; bi=INT_MAX;
  #pragma unroll 4
  for(int c=0;c<V2N/64;c++){
    int i=c*64+lane;
    float4v p=s2[i];
    float dot=qx*p[0]+qy*p[1]+qz*p[2];
    float d=fmaf(-2.0f,dot,p[3]+qs);
    unsigned int k=fkey(d);
    if(k<bk){bk=k;bi=i;}
  }
  #pragma unroll
  for(int s=32;s;s>>=1){
    unsigned int ok=__shfl_xor(bk,s); int oi=__shfl_xor(bi,s);
    if(ok<bk || (ok==bk && oi<bi)){bk=ok;bi=oi;}
  }
  if(lane==0) n2[(size_t)b*V0+j]=bi;
}

// ---------------- conv_surface + outer silu -> fm0 (C=128) ----------------
__global__ __launch_bounds__(128) void conv_surf_k(
    const float* __restrict__ dirn, const float* __restrict__ cnd,
    float* __restrict__ fm0)
{
  int b=blockIdx.y, i=blockIdx.x, t=threadIdx.x;
  __shared__ float sd[32];
  if(t<30) sd[t]=dirn[((size_t)(b*V0+i)*10)*3+t];
  __syncthreads();
  float acc=0.0f;
  for(int s=0;s<SUPN;s++){
    int col=s*128+t;
    float w0=cnd[col], w1c=cnd[896+col], w2c=cnd[1792+col];
    float m=-INFINITY;
    #pragma unroll
    for(int n=0;n<10;n++){
      float d=sd[3*n]*w0+sd[3*n+1]*w1c+sd[3*n+2]*w2c;
      m=fmaxf(m, fast_silu(d));
    }
    acc+=m;
  }
  fm0[(size_t)(b*V0+i)*128+t]=fast_silu(acc);
}

// ---------------- GEMM: C[M,N] = A[M,K] @ W[K,N] + bias[N] (128x128, 8x8/thr) ----
__global__ __launch_bounds__(256) void gemm_bias_k(
    const float* __restrict__ A, const float* __restrict__ W,
    const float* __restrict__ bias, float* __restrict__ C,
    int M, int N, int K)
{
  __shared__ float As[16][132];
  __shared__ float Bs[16][132];
  int t=threadIdx.x;
  int tx=t&15, ty=t>>4;
  int bm=blockIdx.y*128, bn=blockIdx.x*128;
  float4v acc[2][2][4];
  #pragma unroll
  for(int a=0;a<2;a++)
    #pragma unroll
    for(int bidx=0;bidx<2;bidx++)
      #pragma unroll
      for(int m=0;m<4;m++) acc[a][bidx][m]=(float4v)(0.0f);
  int arow=t>>2, akk=(t&3)*4;
  int brow=t>>4, bcol=(t&15)*4;
  for(int k0=0;k0<K;k0+=16){
    float4v a0=*(const float4v*)&A[(size_t)(bm+arow)*K    + k0+akk];
    float4v a1=*(const float4v*)&A[(size_t)(bm+64+arow)*K + k0+akk];
    float4v b0=*(const float4v*)&W[(size_t)(k0+brow)*N + bn+bcol];
    float4v b1=*(const float4v*)&W[(size_t)(k0+brow)*N + bn+64+bcol];
    __syncthreads();
    #pragma unroll
    for(int u=0;u<4;u++){ As[akk+u][arow]=a0[u]; As[akk+u][64+arow]=a1[u]; }
    *(float4v*)&Bs[brow][bcol]=b0;
    *(float4v*)&Bs[brow][64+bcol]=b1;
    __syncthreads();
    #pragma unroll
    for(int kk=0;kk<16;kk++){
      float4v alo=*(const float4v*)&As[kk][ty*4];
      float4v ahi=*(const float4v*)&As[kk][64+ty*4];
      float4v blo=*(const float4v*)&Bs[kk][tx*4];
      float4v bhi=*(const float4v*)&Bs[kk][64+tx*4];
      #pragma unroll
      for(int mi=0;mi<4;mi++){
        acc[0][0][mi] += alo[mi]*blo;
        acc[0][1][mi] += alo[mi]*bhi;
        acc[1][0][mi] += ahi[mi]*blo;
        acc[1][1][mi] += ahi[mi]*bhi;
      }
    }
  }
  float4v bl=*(const float4v*)&bias[bn+tx*4];
  float4v bh=*(const float4v*)&bias[bn+64+tx*4];
  #pragma unroll
  for(int mh=0;mh<2;mh++)
    #pragma unroll
    for(int mi=0;mi<4;mi++){
      size_t row=(size_t)(bm+mh*64+ty*4+mi);
      *(float4v*)&C[row*N + bn+tx*4]    = acc[mh][0][mi]+bl;
      *(float4v*)&C[row*N + bn+64+tx*4] = acc[mh][1][mi]+bh;
    }
}

// ---------------- conv_layer aggregate, vectorized ----------------
// out = center + sum_s max_n silu(dirn.w)*support ; VEC channels per thread.
template<int C, int THREADS>
__global__ __launch_bounds__(THREADS) void conv_agg_k(
    const float* __restrict__ feat,
    int Vb,
    const float* __restrict__ dirn, const int* __restrict__ nbidx,
    const float* __restrict__ cnd,
    float* __restrict__ outp)
{
  constexpr int NC = 8*C;
  constexpr int VEC = C/THREADS;
  constexpr int ncol = SUPN*C;
  int b=blockIdx.y, i=blockIdx.x, t=threadIdx.x;
  __shared__ float sd[32]; __shared__ int snb[10];
  if(t<30) sd[t]=dirn[((size_t)(b*Vb+i)*10)*3+t];
  if(t<10) snb[t]=nbidx[(size_t)(b*Vb+i)*10+t];
  __syncthreads();
  float acc[VEC];
  {
    const float* cptr=&feat[(size_t)(b*Vb+i)*NC + t*VEC];
    #pragma unroll
    for(int v=0;v<VEC;v++) acc[v]=cptr[v];
  }
  const float* fb=feat+(size_t)b*Vb*NC;
  for(int s=0;s<SUPN;s++){
    int colbase = s*C + t*VEC;
    float w0[VEC],w1[VEC],w2[VEC],m[VEC];
    #pragma unroll
    for(int v=0;v<VEC;v++){
      w0[v]=cnd[colbase+v]; w1[v]=cnd[ncol+colbase+v]; w2[v]=cnd[2*ncol+colbase+v];
      m[v]=-INFINITY;
    }
    #pragma unroll
    for(int n=0;n<10;n++){
      float dx=sd[3*n],dy=sd[3*n+1],dz=sd[3*n+2];
      const float* sptr=&fb[(size_t)snb[n]*NC + C + colbase];
      float sup[VEC];
      if(VEC==4){
        float4v sv=*(const float4v*)sptr;
        #pragma unroll
        for(int v=0;v<4;v++) sup[v]=sv[v];
      } else {
        float2v sv=*(const float2v*)sptr;
        #pragma unroll
        for(int v=0;v<VEC;v++) sup[v]=sv[v];
      }
      #pragma unroll
      for(int v=0;v<VEC;v++){
        float d=dx*w0[v]+dy*w1[v]+dz*w2[v];
        m[v]=fmaxf(m[v], fast_silu(d)*sup[v]);
      }
    }
    #pragma unroll
    for(int v=0;v<VEC;v++) acc[v]+=m[v];
  }
  float* optr=&outp[(size_t)(b*Vb+i)*C + t*VEC];
  #pragma unroll
  for(int v=0;v<VEC;v++) optr[v]=acc[v];
}

// ---------------- BN stats ----------------
__global__ void stats_k(const float* __restrict__ xin, int chunk, int C, float* __restrict__ sums)
{
  int t=threadIdx.x;
  size_t r0=(size_t)blockIdx.x*chunk;
  float s=0.0f,s2=0.0f;
  for(int r=0;r<chunk;r++){ float v=xin[(r0+r)*C+t]; s+=v; s2+=v*v; }
  atomicAdd(&sums[t],s); atomicAdd(&sums[C+t],s2);
}

// ---------------- BN apply + silu ----------------
__global__ void bn_silu_k(const float* __restrict__ xin, const float* __restrict__ sums,
                          float invM, int C, const float* __restrict__ g, const float* __restrict__ bb,
                          float* __restrict__ y, int nelem)
{
  int gid=blockIdx.x*blockDim.x+threadIdx.x;
  if(gid>=nelem) return;
  int c=gid&(C-1);
  float mean=sums[c]*invM;
  float var=sums[C+c]*invM - mean*mean;
  float v=(xin[gid]-mean)*rsqrtf(var+1e-5f)*g[c]+bb[c];
  y[gid]=fast_silu(v);
}

// ---------------- pool over first-4 of idx10 at perm rows + coord gather ----------------
__global__ void pool_gather_k(const float* __restrict__ fm, int Vsrc, int C,
                              const int* __restrict__ idx10, const int* __restrict__ perm,
                              const float* __restrict__ vsrc,
                              float* __restrict__ fout, float* __restrict__ vout, int Vq)
{
  int b=blockIdx.y, j=blockIdx.x, t=threadIdx.x;
  int r=perm[j];
  const int* id=idx10+((size_t)b*Vsrc+r)*10;
  const float* fb=fm+(size_t)b*Vsrc*C;
  float m=-INFINITY;
  #pragma unroll
  for(int n=0;n<4;n++) m=fmaxf(m, fb[(size_t)id[n]*C+t]);
  fout[(size_t)(b*Vq+j)*C+t]=m;
  if(t<3) vout[((size_t)b*Vq+j)*3+t]=vsrc[((size_t)b*Vsrc+r)*3+t];
}

// ---------------- final concat with upsampling (float4) ----------------
__global__ __launch_bounds__(320) void concat_k(
    const float* __restrict__ fm0, const float* __restrict__ fm1,
    const float* __restrict__ fm2, const float* __restrict__ fm3,
    const float* __restrict__ fm4,
    const int* __restrict__ n1, const int* __restrict__ n2,
    float* __restrict__ outp)
{
  int b=blockIdx.y, i=blockIdx.x, t=threadIdx.x;
  int j1=n1[b*V0+i], j2=n2[b*V0+i];
  float4v v;
  if(t<64){
    const float* base = (t<32)? fm0 : fm1;
    v = ((const float4v*)(base + (size_t)(b*V0+i)*128))[t&31];
  } else if(t<192){
    const float* base = (t<128)? fm2 : fm3;
    v = ((const float4v*)(base + ((size_t)b*V1N+j1)*256))[(t-64)&63];
  } else {
    v = ((const float4v*)(fm4 + ((size_t)b*V2N+j2)*512))[t-192];
  }
  ((float4v*)(outp + (size_t)(b*V0+i)*1280))[t] = v;
}

extern "C" void kernel_launch(void* const* d_in, const int* in_sizes, int n_in,
                              void* d_out, int out_size, void* d_ws, size_t ws_size,
                              hipStream_t stream) {
  const float* x   =(const float*)d_in[0];
  const float* d0  =(const float*)d_in[1];
  const float* w1  =(const float*)d_in[2];
  const float* b1  =(const float*)d_in[3];
  const float* dir1=(const float*)d_in[4];
  const float* g1  =(const float*)d_in[5];
  const float* bb1 =(const float*)d_in[6];
  const float* w2  =(const float*)d_in[7];
  const float* b2  =(const float*)d_in[8];
  const float* dir2=(const float*)d_in[9];
  const float* g2  =(const float*)d_in[10];
  const float* bb2 =(const float*)d_in[11];
  const float* w3  =(const float*)d_in[12];
  const float* b3  =(const float*)d_in[13];
  const float* dir3=(const float*)d_in[14];
  const float* g3  =(const float*)d_in[15];
  const float* bb3 =(const float*)d_in[16];
  const float* w4  =(const float*)d_in[17];
  const float* b4  =(const float*)d_in[18];
  const float* dir4=(const float*)d_in[19];
  const int* perm1 =(const int*)d_in[20];
  const int* perm2 =(const int*)d_in[21];
  float* out=(float*)d_out;

  float* w=(float*)d_ws;
  size_t off=0;
  auto alloc=[&](size_t n){ float* p=w+off; off+=n; return p; };
  float* cn0 =alloc(2688);
  float* cn1 =alloc(2688);
  float* cn2 =alloc(5376);
  float* cn3 =alloc(5376);
  float* cn4 =alloc(10752);
  float* dirnx =alloc((size_t)BNUM*V0*30);
  float* dirnv1=alloc((size_t)BNUM*V1N*30);
  float* dirnv2=alloc((size_t)BNUM*V2N*30);
  float* fm0 =alloc((size_t)BNUM*V0*128);
  float* feat=alloc((size_t)BNUM*V0*1024);
  float* fm1r=alloc((size_t)BNUM*V0*128);
  float* fm1 =alloc((size_t)BNUM*V0*128);
  float* f1  =alloc((size_t)BNUM*V1N*128);
  float* v1  =alloc((size_t)BNUM*V1N*3);
  float* fm2r=alloc((size_t)BNUM*V1N*256);
  float* fm2 =alloc((size_t)BNUM*V1N*256);
  float* fm3r=alloc((size_t)BNUM*V1N*256);
  float* fm3 =alloc((size_t)BNUM*V1N*256);
  float* f2  =alloc((size_t)BNUM*V2N*256);
  float* v2  =alloc((size_t)BNUM*V2N*3);
  float* fm4 =alloc((size_t)BNUM*V2N*512);
  float* stats=alloc(1280);
  int* idx10x =(int*)alloc((size_t)BNUM*V0*10);
  int* idx10v1=(int*)alloc((size_t)BNUM*V1N*10);
  int* idx10v2=(int*)alloc((size_t)BNUM*V2N*10);
  int* n1i =(int*)alloc((size_t)BNUM*V0);
  int* n2i =(int*)alloc((size_t)BNUM*V0);

  colnorm_all_k<<<dim3(35),256,0,stream>>>(d0,dir1,dir2,dir3,dir4,cn0,cn1,cn2,cn3,cn4,stats);

  // knn10 on x
  knn10_k<V0,1024><<<dim3(V0/16,BNUM),1024,0,stream>>>(x, idx10x, dirnx);
  conv_surf_k<<<dim3(V0,BNUM),128,0,stream>>>(dirnx, cn0, fm0);

  // layer 1
  gemm_bias_k<<<dim3(1024/128,(BNUM*V0)/128),256,0,stream>>>(fm0, w1, b1, feat, BNUM*V0, 1024, 128);
  conv_agg_k<128,64><<<dim3(V0,BNUM),64,0,stream>>>(feat, V0, dirnx, idx10x, cn1, fm1r);
  stats_k<<<dim3((BNUM*V0)/64),128,0,stream>>>(fm1r, 64, 128, stats);
  bn_silu_k<<<dim3((BNUM*V0*128)/256),256,0,stream>>>(fm1r, stats, 1.0f/(BNUM*V0), 128, g1, bb1, fm1, BNUM*V0*128);

  // pool (first-4 of idx10x at perm1) + v1 gather
  pool_gather_k<<<dim3(V1N,BNUM),128,0,stream>>>(fm1, V0, 128, idx10x, perm1, x, f1, v1, V1N);

  // knn10 on v1
  knn10_k<V1N,512><<<dim3(V1N/8,BNUM),512,0,stream>>>(v1, idx10v1, dirnv1);

  // layer 2
  gemm_bias_k<<<dim3(2048/128,(BNUM*V1N)/128),256,0,stream>>>(f1, w2, b2, feat, BNUM*V1N, 2048, 128);
  conv_agg_k<256,64><<<dim3(V1N,BNUM),64,0,stream>>>(feat, V1N, dirnv1, idx10v1, cn2, fm2r);
  stats_k<<<dim3((BNUM*V1N)/64),256,0,stream>>>(fm2r, 64, 256, stats+256);
  bn_silu_k<<<dim3((BNUM*V1N*256)/256),256,0,stream>>>(fm2r, stats+256, 1.0f/(BNUM*V1N), 256, g2, bb2, fm2, BNUM*V1N*256);

  // layer 3
  gemm_bias_k<<<dim3(2048/128,(BNUM*V1N)/128),256,0,stream>>>(fm2, w3, b3, feat, BNUM*V1N, 2048, 256);
  conv_agg_k<256,64><<<dim3(V1N,BNUM),64,0,stream>>>(feat, V1N, dirnv1, idx10v1, cn3, fm3r);
  stats_k<<<dim3((BNUM*V1N)/64),256,0,stream>>>(fm3r, 64, 256, stats+768);
  bn_silu_k<<<dim3((BNUM*V1N*256)/256),256,0,stream>>>(fm3r, stats+768, 1.0f/(BNUM*V1N), 256, g3, bb3, fm3, BNUM*V1N*256);

  // pool (first-4 of idx10v1 at perm2) + v2 gather
  pool_gather_k<<<dim3(V2N,BNUM),256,0,stream>>>(fm3, V1N, 256, idx10v1, perm2, v1, f2, v2, V2N);

  // knn10 on v2
  knn10_k<V2N,256><<<dim3(V2N/4,BNUM),256,0,stream>>>(v2, idx10v2, dirnv2);

  // layer 4 (no bn/silu)
  gemm_bias_k<<<dim3(4096/128,(BNUM*V2N)/128),256,0,stream>>>(f2, w4, b4, feat, BNUM*V2N, 4096, 256);
  conv_agg_k<512,128><<<dim3(V2N,BNUM),128,0,stream>>>(feat, V2N, dirnv2, idx10v2, cn4, fm4);

  // fused nearest upsample indices
  nearest_both_k<<<dim3(V0/8,BNUM),512,0,stream>>>(v1, v2, x, n1i, n2i);

  // final concat
  concat_k<<<dim3(V0,BNUM),320,0,stream>>>(fm0, fm1, fm2, fm3, fm4, n1i, n2i, out);
}

// Round 5
// 591.849 us; speedup vs baseline: 1.3362x; 1.1251x over previous
//
#include <hip/hip_runtime.h>
#include <math.h>
#include <float.h>
#include <limits.h>

#define BNUM 2
#define V0 4096
#define V1N 1024
#define V2N 256
#define SUPN 7

typedef float float4v __attribute__((ext_vector_type(4)));
typedef float float2v __attribute__((ext_vector_type(2)));
typedef unsigned long long u64;

__device__ __forceinline__ float fast_silu(float x){
  return __fdividef(x, 1.0f + __expf(-x));
}

// exact monotone float->uint transform: a<b (float) <=> key(a)<key(b) (uint)
__device__ __forceinline__ unsigned int fkey(float f){
  unsigned int u = __float_as_uint(f);
  int m = ((int)u) >> 31;
  return u ^ (unsigned int)(m | 0x80000000);
}

__device__ __forceinline__ u64 shfl_xor_u64(u64 v, int m){
  unsigned int lo = (unsigned int)v, hi = (unsigned int)(v>>32);
  lo = (unsigned int)__shfl_xor((int)lo, m);
  hi = (unsigned int)__shfl_xor((int)hi, m);
  return ((u64)hi<<32) | lo;
}

// ---------------- fused column-normalize + stats zero ----------------
__global__ void colnorm_all_k(const float* __restrict__ d0, const float* __restrict__ dir1,
                              const float* __restrict__ dir2, const float* __restrict__ dir3,
                              const float* __restrict__ dir4,
                              float* __restrict__ cn0, float* __restrict__ cn1,
                              float* __restrict__ cn2, float* __restrict__ cn3,
                              float* __restrict__ cn4, float* __restrict__ stats){
  int c = blockIdx.x*256 + threadIdx.x;
  if(c < 1280) stats[c] = 0.0f;
  const float* s; float* o; int nc;
  if(c < 896){ s=d0; o=cn0; nc=896; }
  else if((c-=896) < 896){ s=dir1; o=cn1; nc=896; }
  else if((c-=896) < 1792){ s=dir2; o=cn2; nc=1792; }
  else if((c-=1792) < 1792){ s=dir3; o=cn3; nc=1792; }
  else { c-=1792; if(c>=3584) return; s=dir4; o=cn4; nc=3584; }
  float a=s[c], b=s[nc+c], e=s[2*nc+c];
  float n=sqrtf(a*a+b*b+e*e); n=fmaxf(n,1e-12f);
  o[c]=a/n; o[nc+c]=b/n; o[2*nc+c]=e/n;
}

// ---------------- self-KNN (k=10, skip self), u64 (key|idx) version ----------------
// LDS holds (x,y,z,|c|^2) float4 per point. One wave per query.
// Per-lane branchless top-4 on u64 keys; 11 shuffle-argmin rounds; exact fallback.
template<int VC, int THREADS>
__global__ __launch_bounds__(THREADS) void knn10_k(const float* __restrict__ pts,
    int* __restrict__ out_idx, float* __restrict__ out_dirn)
{
  constexpr int CHUNK = VC/64;
  constexpr int QPB = THREADS/64;
  constexpr int TOT = 11;
  __shared__ float4v sp4[VC];
  int t = threadIdx.x;
  int lane = t & 63;
  int wv   = t >> 6;
  int b = blockIdx.y;
  int j = blockIdx.x*QPB + wv;
  const float* pb = pts + (size_t)b*VC*3;
  for(int i=t; i<VC; i+=THREADS){
    float x=pb[3*i], y=pb[3*i+1], z=pb[3*i+2];
    float4v v; v[0]=x; v[1]=y; v[2]=z; v[3]=x*x+y*y+z*z;
    sp4[i]=v;
  }
  __syncthreads();
  float qx=pb[3*j], qy=pb[3*j+1], qz=pb[3*j+2];
  float qs=qx*qx+qy*qy+qz*qz;

  u64 p0=~0ull,p1=~0ull,p2=~0ull,p3=~0ull;
  #pragma unroll 4
  for(int c=0;c<CHUNK;c++){
    int i = c*64 + lane;
    float4v p = sp4[i];
    float dot = qx*p[0]+qy*p[1]+qz*p[2];
    float d = fmaf(-2.0f, dot, p[3]+qs);
    u64 k = ((u64)fkey(d)<<32) | (unsigned int)i;
    // branchless sorted insert into p0<=p1<=p2<=p3
    p3 = k<p3 ? k : p3;
    { u64 a=p2<p3?p2:p3, q=p2<p3?p3:p2; p2=a; p3=q; }
    { u64 a=p1<p2?p1:p2, q=p1<p2?p2:p1; p1=a; p2=q; }
    { u64 a=p0<p1?p0:p1, q=p0<p1?p1:p0; p0=a; p1=q; }
  }
  // extraction: 11 rounds of wave-argmin over "smallest pool entry > prev"
  u64 prev=0ull, wkey=0ull;
  for(int sel=0; sel<TOT; ++sel){
    u64 c = p0>prev?p0:(p1>prev?p1:(p2>prev?p2:(p3>prev?p3:~0ull)));
    #pragma unroll
    for(int s=32;s;s>>=1){
      u64 o = shfl_xor_u64(c,s);
      c = o<c ? o : c;
    }
    if(lane==sel) wkey=c;
    prev=c;
  }
  // exactness guard: lane's pool exhausted at/below the 11th selected
  if(__any(p3<=prev)){
    prev=0ull;
    for(int sel=0; sel<TOT; ++sel){
      u64 c=~0ull;
      for(int cc=0;cc<CHUNK;cc++){
        int i=cc*64+lane;
        float4v p = sp4[i];
        float dot = qx*p[0]+qy*p[1]+qz*p[2];
        float d = fmaf(-2.0f, dot, p[3]+qs);
        u64 k = ((u64)fkey(d)<<32) | (unsigned int)i;
        if(k>prev && k<c) c=k;
      }
      #pragma unroll
      for(int s=32;s;s>>=1){
        u64 o = shfl_xor_u64(c,s);
        c = o<c ? o : c;
      }
      if(lane==sel) wkey=c;
      prev=c;
    }
  }
  if(lane>=1 && lane<TOT){
    int wi=(int)(wkey & 0xffffffffu);
    size_t obase=((size_t)b*VC+j)*10 + (lane-1);
    out_idx[obase]=wi;
    float4v p = sp4[wi];
    float dx=p[0]-qx, dy=p[1]-qy, dz=p[2]-qz;
    float n=sqrtf(dx*dx+dy*dy+dz*dz); n=fmaxf(n,1e-12f);
    out_dirn[obase*3]=dx/n; out_dirn[obase*3+1]=dy/n; out_dirn[obase*3+2]=dz/n;
  }
}

// ---------------- fused nearest for v1 and v2 (argmin, ties -> lower index) ----------
__global__ __launch_bounds__(512) void nearest_both_k(
    const float* __restrict__ v1, const float* __restrict__ v2,
    const float* __restrict__ x,
    int* __restrict__ n1, int* __restrict__ n2)
{
  __shared__ float4v s1[V1N];
  __shared__ float4v s2[V2N];
  int t=threadIdx.x;
  int lane=t&63, wv=t>>6;
  int b=blockIdx.y; int j=blockIdx.x*8+wv;
  const float* c1=v1+(size_t)b*V1N*3;
  const float* c2=v2+(size_t)b*V2N*3;
  for(int i=t;i<V1N;i+=512){
    float xx=c1[3*i],yy=c1[3*i+1],zz=c1[3*i+2];
    float4v v; v[0]=xx;v[1]=yy;v[2]=zz;v[3]=xx*xx+yy*yy+zz*zz; s1[i]=v;
  }
  for(int i=t;i<V2N;i+=512){
    float xx=c2[3*i],yy=c2[3*i+1],zz=c2[3*i+2];
    float4v v; v[0]=xx;v[1]=yy;v[2]=zz;v[3]=xx*xx+yy*yy+zz*zz; s2[i]=v;
  }
  __syncthreads();
  const float* qb=x+(size_t)b*V0*3;
  float qx=qb[3*j],qy=qb[3*j+1],qz=qb[3*j+2];
  float qs=qx*qx+qy*qy+qz*qz;
  u64 bk=~0ull;
  #pragma unroll 4
  for(int c=0;c<V1N/64;c++){
    int i=c*64+lane;
    float4v p=s1[i];
    float dot=qx*p[0]+qy*p[1]+qz*p[2];
    float d=fmaf(-2.0f,dot,p[3]+qs);
    u64 k=((u64)fkey(d)<<32)|(unsigned int)i;
    bk = k<bk ? k : bk;
  }
  #pragma unroll
  for(int s=32;s;s>>=1){ u64 o=shfl_xor_u64(bk,s); bk = o<bk?o:bk; }
  if(lane==0) n1[(size_t)b*V0+j]=(int)(bk&0xffffffffu);
  bk=~0ull;
  #pragma unroll 4
  for(int c=0;c<V2N/64;c++){
    int i=c*64+lane;
    float4v p=s2[i];
    float dot=qx*p[0]+qy*p[1]+qz*p[2];
    float d=fmaf(-2.0f,dot,p[3]+qs);
    u64 k=((u64)fkey(d)<<32)|(unsigned int)i;
    bk = k<bk ? k : bk;
  }
  #pragma unroll
  for(int s=32;s;s>>=1){ u64 o=shfl_xor_u64(bk,s); bk = o<bk?o:bk; }
  if(lane==0) n2[(size_t)b*V0+j]=(int)(bk&0xffffffffu);
}

// ---------------- conv_surface + outer silu -> fm0 + out[:, :128] ----------------
// NODES nodes per block, 64 threads/node, 2 channels/lane.
template<int NODES>
__global__ __launch_bounds__(64*NODES) void conv_surf_k(
    const float* __restrict__ dirn, const float* __restrict__ cnd,
    float* __restrict__ fm0, float* __restrict__ outbuf)
{
  int tid=threadIdx.x, nd=tid>>6, t=tid&63;
  int b=blockIdx.y, i=blockIdx.x*NODES+nd;
  __shared__ float sd[NODES][32];
  if(t<30) sd[nd][t]=dirn[((size_t)(b*V0+i))*30+t];
  __syncthreads();
  float acc0=0.0f, acc1=0.0f;
  for(int s=0;s<SUPN;s++){
    int col=s*128+t;
    float wa0=cnd[col],     wa1=cnd[896+col],     wa2=cnd[1792+col];
    float wb0=cnd[col+64],  wb1=cnd[896+col+64],  wb2=cnd[1792+col+64];
    float m0=-INFINITY, m1=-INFINITY;
    #pragma unroll
    for(int n=0;n<10;n++){
      float dx=sd[nd][3*n], dy=sd[nd][3*n+1], dz=sd[nd][3*n+2];
      m0=fmaxf(m0, fast_silu(dx*wa0+dy*wa1+dz*wa2));
      m1=fmaxf(m1, fast_silu(dx*wb0+dy*wb1+dz*wb2));
    }
    acc0+=m0; acc1+=m1;
  }
  float r0=fast_silu(acc0), r1=fast_silu(acc1);
  size_t frow=(size_t)(b*V0+i)*128;
  fm0[frow+t]=r0; fm0[frow+64+t]=r1;
  size_t orow=(size_t)(b*V0+i)*1280;
  outbuf[orow+t]=r0; outbuf[orow+64+t]=r1;
}

// ---------------- GEMM: C[M,N] = A[M,K] @ W[K,N] + bias[N] (128x128, 8x8/thr) ----
__global__ __launch_bounds__(256) void gemm_bias_k(
    const float* __restrict__ A, const float* __restrict__ W,
    const float* __restrict__ bias, float* __restrict__ C,
    int M, int N, int K)
{
  __shared__ float As[16][132];
  __shared__ float Bs[16][132];
  int t=threadIdx.x;
  int tx=t&15, ty=t>>4;
  int bm=blockIdx.y*128, bn=blockIdx.x*128;
  float4v acc[2][2][4];
  #pragma unroll
  for(int a=0;a<2;a++)
    #pragma unroll
    for(int bidx=0;bidx<2;bidx++)
      #pragma unroll
      for(int m=0;m<4;m++) acc[a][bidx][m]=(float4v)(0.0f);
  int arow=t>>2, akk=(t&3)*4;
  int brow=t>>4, bcol=(t&15)*4;
  for(int k0=0;k0<K;k0+=16){
    float4v a0=*(const float4v*)&A[(size_t)(bm+arow)*K    + k0+akk];
    float4v a1=*(const float4v*)&A[(size_t)(bm+64+arow)*K + k0+akk];
    float4v b0=*(const float4v*)&W[(size_t)(k0+brow)*N + bn+bcol];
    float4v b1=*(const float4v*)&W[(size_t)(k0+brow)*N + bn+64+bcol];
    __syncthreads();
    #pragma unroll
    for(int u=0;u<4;u++){ As[akk+u][arow]=a0[u]; As[akk+u][64+arow]=a1[u]; }
    *(float4v*)&Bs[brow][bcol]=b0;
    *(float4v*)&Bs[brow][64+bcol]=b1;
    __syncthreads();
    #pragma unroll
    for(int kk=0;kk<16;kk++){
      float4v alo=*(const float4v*)&As[kk][ty*4];
      float4v ahi=*(const float4v*)&As[kk][64+ty*4];
      float4v blo=*(const float4v*)&Bs[kk][tx*4];
      float4v bhi=*(const float4v*)&Bs[kk][64+tx*4];
      #pragma unroll
      for(int mi=0;mi<4;mi++){
        acc[0][0][mi] += alo[mi]*blo;
        acc[0][1][mi] += alo[mi]*bhi;
        acc[1][0][mi] += ahi[mi]*blo;
        acc[1][1][mi] += ahi[mi]*bhi;
      }
    }
  }
  float4v bl=*(const float4v*)&bias[bn+tx*4];
  float4v bh=*(const float4v*)&bias[bn+64+tx*4];
  #pragma unroll
  for(int mh=0;mh<2;mh++)
    #pragma unroll
    for(int mi=0;mi<4;mi++){
      size_t row=(size_t)(bm+mh*64+ty*4+mi);
      *(float4v*)&C[row*N + bn+tx*4]    = acc[mh][0][mi]+bl;
      *(float4v*)&C[row*N + bn+64+tx*4] = acc[mh][1][mi]+bh;
    }
}

// ---------------- conv_layer aggregate, multi-node vectorized ----------------
template<int C, int TPN, int NODES>
__global__ __launch_bounds__(TPN*NODES) void conv_agg_k(
    const float* __restrict__ feat, int Vb,
    const float* __restrict__ dirn, const int* __restrict__ nbidx,
    const float* __restrict__ cnd,
    float* __restrict__ outp)
{
  constexpr int NC = 8*C;
  constexpr int VEC = C/TPN;
  constexpr int ncol = SUPN*C;
  int tid=threadIdx.x, nd=tid/TPN, t=tid%TPN;
  int b=blockIdx.y, i=blockIdx.x*NODES+nd;
  __shared__ float sd[NODES][32];
  __shared__ int snb[NODES][12];
  if(t<30) sd[nd][t]=dirn[((size_t)(b*Vb+i))*30+t];
  if(t<10) snb[nd][t]=nbidx[(size_t)(b*Vb+i)*10+t];
  __syncthreads();
  float acc[VEC];
  {
    const float* cptr=&feat[(size_t)(b*Vb+i)*NC + t*VEC];
    if(VEC==4){ float4v cv=*(const float4v*)cptr;
      #pragma unroll
      for(int v=0;v<4;v++) acc[v]=cv[v];
    } else { float2v cv=*(const float2v*)cptr;
      #pragma unroll
      for(int v=0;v<VEC;v++) acc[v]=cv[v];
    }
  }
  const float* fb=feat+(size_t)b*Vb*NC;
  for(int s=0;s<SUPN;s++){
    int colbase = s*C + t*VEC;
    float w0[VEC],w1[VEC],w2[VEC],m[VEC];
    #pragma unroll
    for(int v=0;v<VEC;v++){
      w0[v]=cnd[colbase+v]; w1[v]=cnd[ncol+colbase+v]; w2[v]=cnd[2*ncol+colbase+v];
      m[v]=-INFINITY;
    }
    #pragma unroll
    for(int n=0;n<10;n++){
      float dx=sd[nd][3*n],dy=sd[nd][3*n+1],dz=sd[nd][3*n+2];
      const float* sptr=&fb[(size_t)snb[nd][n]*NC + C + colbase];
      float sup[VEC];
      if(VEC==4){
        float4v sv=*(const float4v*)sptr;
        #pragma unroll
        for(int v=0;v<4;v++) sup[v]=sv[v];
      } else {
        float2v sv=*(const float2v*)sptr;
        #pragma unroll
        for(int v=0;v<VEC;v++) sup[v]=sv[v];
      }
      #pragma unroll
      for(int v=0;v<VEC;v++){
        float d=dx*w0[v]+dy*w1[v]+dz*w2[v];
        m[v]=fmaxf(m[v], fast_silu(d)*sup[v]);
      }
    }
    #pragma unroll
    for(int v=0;v<VEC;v++) acc[v]+=m[v];
  }
  float* optr=&outp[(size_t)(b*Vb+i)*C + t*VEC];
  if(VEC==4){ float4v ov; 
    #pragma unroll
    for(int v=0;v<4;v++) ov[v]=acc[v];
    *(float4v*)optr=ov;
  } else { float2v ov;
    #pragma unroll
    for(int v=0;v<VEC;v++) ov[v]=acc[v];
    *(float2v*)optr=ov;
  }
}

// ---------------- BN stats ----------------
__global__ void stats_k(const float* __restrict__ xin, int chunk, int C, float* __restrict__ sums)
{
  int t=threadIdx.x;
  size_t r0=(size_t)blockIdx.x*chunk;
  float s=0.0f,s2=0.0f;
  for(int r=0;r<chunk;r++){ float v=xin[(r0+r)*C+t]; s+=v; s2+=v*v; }
  atomicAdd(&sums[t],s); atomicAdd(&sums[C+t],s2);
}

// ---------------- BN apply + silu (+ optional out-slice write) ----------------
__global__ void bn_silu_k(const float* __restrict__ xin, const float* __restrict__ sums,
                          float invM, int C, const float* __restrict__ g, const float* __restrict__ bb,
                          float* __restrict__ y, int nelem, float* __restrict__ osl, int cshift)
{
  int gid=blockIdx.x*blockDim.x+threadIdx.x;
  if(gid>=nelem) return;
  int c=gid&(C-1);
  float mean=sums[c]*invM;
  float var=sums[C+c]*invM - mean*mean;
  float v=(xin[gid]-mean)*rsqrtf(var+1e-5f)*g[c]+bb[c];
  float r=fast_silu(v);
  y[gid]=r;
  if(osl) osl[((size_t)(gid>>cshift))*1280 + c]=r;
}

// ---------------- pool over first-4 of idx10 at perm rows + coord gather ----------------
__global__ void pool_gather_k(const float* __restrict__ fm, int Vsrc, int C,
                              const int* __restrict__ idx10, const int* __restrict__ perm,
                              const float* __restrict__ vsrc,
                              float* __restrict__ fout, float* __restrict__ vout, int Vq)
{
  int b=blockIdx.y, j=blockIdx.x, t=threadIdx.x;
  int r=perm[j];
  const int* id=idx10+((size_t)b*Vsrc+r)*10;
  const float* fb=fm+(size_t)b*Vsrc*C;
  float m=-INFINITY;
  #pragma unroll
  for(int n=0;n<4;n++) m=fmaxf(m, fb[(size_t)id[n]*C+t]);
  fout[(size_t)(b*Vq+j)*C+t]=m;
  if(t<3) vout[((size_t)b*Vq+j)*3+t]=vsrc[((size_t)b*Vsrc+r)*3+t];
}

// ---------------- final concat: only fm2/fm3/fm4 upsampled slices ----------------
__global__ __launch_bounds__(256) void concat_k(
    const float* __restrict__ fm2, const float* __restrict__ fm3,
    const float* __restrict__ fm4,
    const int* __restrict__ n1, const int* __restrict__ n2,
    float* __restrict__ outp)
{
  int b=blockIdx.y, i=blockIdx.x, t=threadIdx.x;
  int j1=n1[b*V0+i], j2=n2[b*V0+i];
  float4v v;
  if(t<64)       v = ((const float4v*)(fm2 + ((size_t)b*V1N+j1)*256))[t];
  else if(t<128) v = ((const float4v*)(fm3 + ((size_t)b*V1N+j1)*256))[t-64];
  else           v = ((const float4v*)(fm4 + ((size_t)b*V2N+j2)*512))[t-128];
  ((float4v*)(outp + (size_t)(b*V0+i)*1280))[64+t] = v;
}

extern "C" void kernel_launch(void* const* d_in, const int* in_sizes, int n_in,
                              void* d_out, int out_size, void* d_ws, size_t ws_size,
                              hipStream_t stream) {
  const float* x   =(const float*)d_in[0];
  const float* d0  =(const float*)d_in[1];
  const float* w1  =(const float*)d_in[2];
  const float* b1  =(const float*)d_in[3];
  const float* dir1=(const float*)d_in[4];
  const float* g1  =(const float*)d_in[5];
  const float* bb1 =(const float*)d_in[6];
  const float* w2  =(const float*)d_in[7];
  const float* b2  =(const float*)d_in[8];
  const float* dir2=(const float*)d_in[9];
  const float* g2  =(const float*)d_in[10];
  const float* bb2 =(const float*)d_in[11];
  const float* w3  =(const float*)d_in[12];
  const float* b3  =(const float*)d_in[13];
  const float* dir3=(const float*)d_in[14];
  const float* g3  =(const float*)d_in[15];
  const float* bb3 =(const float*)d_in[16];
  const float* w4  =(const float*)d_in[17];
  const float* b4  =(const float*)d_in[18];
  const float* dir4=(const float*)d_in[19];
  const int* perm1 =(const int*)d_in[20];
  const int* perm2 =(const int*)d_in[21];
  float* out=(float*)d_out;

  float* w=(float*)d_ws;
  size_t off=0;
  auto alloc=[&](size_t n){ float* p=w+off; off+=n; return p; };
  float* cn0 =alloc(2688);
  float* cn1 =alloc(2688);
  float* cn2 =alloc(5376);
  float* cn3 =alloc(5376);
  float* cn4 =alloc(10752);
  float* dirnx =alloc((size_t)BNUM*V0*30);
  float* dirnv1=alloc((size_t)BNUM*V1N*30);
  float* dirnv2=alloc((size_t)BNUM*V2N*30);
  float* fm0 =alloc((size_t)BNUM*V0*128);
  float* feat=alloc((size_t)BNUM*V0*1024);
  float* fm1r=alloc((size_t)BNUM*V0*128);
  float* fm1 =alloc((size_t)BNUM*V0*128);
  float* f1  =alloc((size_t)BNUM*V1N*128);
  float* v1  =alloc((size_t)BNUM*V1N*3);
  float* fm2r=alloc((size_t)BNUM*V1N*256);
  float* fm2 =alloc((size_t)BNUM*V1N*256);
  float* fm3r=alloc((size_t)BNUM*V1N*256);
  float* fm3 =alloc((size_t)BNUM*V1N*256);
  float* f2  =alloc((size_t)BNUM*V2N*256);
  float* v2  =alloc((size_t)BNUM*V2N*3);
  float* fm4 =alloc((size_t)BNUM*V2N*512);
  float* stats=alloc(1280);
  int* idx10x =(int*)alloc((size_t)BNUM*V0*10);
  int* idx10v1=(int*)alloc((size_t)BNUM*V1N*10);
  int* idx10v2=(int*)alloc((size_t)BNUM*V2N*10);
  int* n1i =(int*)alloc((size_t)BNUM*V0);
  int* n2i =(int*)alloc((size_t)BNUM*V0);

  colnorm_all_k<<<dim3(35),256,0,stream>>>(d0,dir1,dir2,dir3,dir4,cn0,cn1,cn2,cn3,cn4,stats);

  // knn10 on x
  knn10_k<V0,1024><<<dim3(V0/16,BNUM),1024,0,stream>>>(x, idx10x, dirnx);
  // fm0 = silu(conv_surface) -> fm0 scratch + out[:, :128]
  conv_surf_k<4><<<dim3(V0/4,BNUM),256,0,stream>>>(dirnx, cn0, fm0, out);

  // layer 1
  gemm_bias_k<<<dim3(1024/128,(BNUM*V0)/128),256,0,stream>>>(fm0, w1, b1, feat, BNUM*V0, 1024, 128);
  conv_agg_k<128,64,4><<<dim3(V0/4,BNUM),256,0,stream>>>(feat, V0, dirnx, idx10x, cn1, fm1r);
  stats_k<<<dim3((BNUM*V0)/64),128,0,stream>>>(fm1r, 64, 128, stats);
  bn_silu_k<<<dim3((BNUM*V0*128)/256),256,0,stream>>>(fm1r, stats, 1.0f/(BNUM*V0), 128, g1, bb1, fm1, BNUM*V0*128, out+128, 7);

  // pool (first-4 of idx10x at perm1) + v1 gather
  pool_gather_k<<<dim3(V1N,BNUM),128,0,stream>>>(fm1, V0, 128, idx10x, perm1, x, f1, v1, V1N);

  // knn10 on v1
  knn10_k<V1N,256><<<dim3(V1N/4,BNUM),256,0,stream>>>(v1, idx10v1, dirnv1);

  // layer 2
  gemm_bias_k<<<dim3(2048/128,(BNUM*V1N)/128),256,0,stream>>>(f1, w2, b2, feat, BNUM*V1N, 2048, 128);
  conv_agg_k<256,64,4><<<dim3(V1N/4,BNUM),256,0,stream>>>(feat, V1N, dirnv1, idx10v1, cn2, fm2r);
  stats_k<<<dim3((BNUM*V1N)/64),256,0,stream>>>(fm2r, 64, 256, stats+256);
  bn_silu_k<<<dim3((BNUM*V1N*256)/256),256,0,stream>>>(fm2r, stats+256, 1.0f/(BNUM*V1N), 256, g2, bb2, fm2, BNUM*V1N*256, nullptr, 8);

  // layer 3
  gemm_bias_k<<<dim3(2048/128,(BNUM*V1N)/128),256,0,stream>>>(fm2, w3, b3, feat, BNUM*V1N, 2048, 256);
  conv_agg_k<256,64,4><<<dim3(V1N/4,BNUM),256,0,stream>>>(feat, V1N, dirnv1, idx10v1, cn3, fm3r);
  stats_k<<<dim3((BNUM*V1N)/64),256,0,stream>>>(fm3r, 64, 256, stats+768);
  bn_silu_k<<<dim3((BNUM*V1N*256)/256),256,0,stream>>>(fm3r, stats+768, 1.0f/(BNUM*V1N), 256, g3, bb3, fm3, BNUM*V1N*256, nullptr, 8);

  // pool (first-4 of idx10v1 at perm2) + v2 gather
  pool_gather_k<<<dim3(V2N,BNUM),256,0,stream>>>(fm3, V1N, 256, idx10v1, perm2, v1, f2, v2, V2N);

  // knn10 on v2
  knn10_k<V2N,256><<<dim3(V2N/4,BNUM),256,0,stream>>>(v2, idx10v2, dirnv2);

  // layer 4 (no bn/silu)
  gemm_bias_k<<<dim3(4096/128,(BNUM*V2N)/128),256,0,stream>>>(f2, w4, b4, feat, BNUM*V2N, 4096, 256);
  conv_agg_k<512,128,2><<<dim3(V2N/2,BNUM),256,0,stream>>>(feat, V2N, dirnv2, idx10v2, cn4, fm4);

  // fused nearest upsample indices
  nearest_both_k<<<dim3(V0/8,BNUM),512,0,stream>>>(v1, v2, x, n1i, n2i);

  // final concat (fm2/fm3/fm4 slices only)
  concat_k<<<dim3(V0,BNUM),256,0,stream>>>(fm2, fm3, fm4, n1i, n2i, out);
}

// Round 6
// 576.325 us; speedup vs baseline: 1.3722x; 1.0269x over previous
//
#include <hip/hip_runtime.h>
#include <math.h>
#include <float.h>
#include <limits.h>

#define BNUM 2
#define V0 4096
#define V1N 1024
#define V2N 256
#define SUPN 7

typedef float float4v __attribute__((ext_vector_type(4)));
typedef float float2v __attribute__((ext_vector_type(2)));
typedef unsigned long long u64;

__device__ __forceinline__ float fast_silu(float x){
  return __fdividef(x, 1.0f + __expf(-x));
}

// exact monotone float->uint transform: a<b (float) <=> key(a)<key(b) (uint)
__device__ __forceinline__ unsigned int fkey(float f){
  unsigned int u = __float_as_uint(f);
  int m = ((int)u) >> 31;
  return u ^ (unsigned int)(m | 0x80000000);
}

__device__ __forceinline__ u64 shfl_xor_u64(u64 v, int m){
  unsigned int lo = (unsigned int)v, hi = (unsigned int)(v>>32);
  lo = (unsigned int)__shfl_xor((int)lo, m);
  hi = (unsigned int)__shfl_xor((int)hi, m);
  return ((u64)hi<<32) | lo;
}

// ---------------- fused column-normalize + stats zero ----------------
__global__ void colnorm_all_k(const float* __restrict__ d0, const float* __restrict__ dir1,
                              const float* __restrict__ dir2, const float* __restrict__ dir3,
                              const float* __restrict__ dir4,
                              float* __restrict__ cn0, float* __restrict__ cn1,
                              float* __restrict__ cn2, float* __restrict__ cn3,
                              float* __restrict__ cn4, float* __restrict__ stats){
  int c = blockIdx.x*256 + threadIdx.x;
  if(c < 1280) stats[c] = 0.0f;
  const float* s; float* o; int nc;
  if(c < 896){ s=d0; o=cn0; nc=896; }
  else if((c-=896) < 896){ s=dir1; o=cn1; nc=896; }
  else if((c-=896) < 1792){ s=dir2; o=cn2; nc=1792; }
  else if((c-=1792) < 1792){ s=dir3; o=cn3; nc=1792; }
  else { c-=1792; if(c>=3584) return; s=dir4; o=cn4; nc=3584; }
  float a=s[c], b=s[nc+c], e=s[2*nc+c];
  float n=sqrtf(a*a+b*b+e*e); n=fmaxf(n,1e-12f);
  o[c]=a/n; o[nc+c]=b/n; o[2*nc+c]=e/n;
}

// ---------------- self-KNN (k=10, skip self), u64 keys + branchy insert ----------------
template<int VC, int THREADS>
__global__ __launch_bounds__(THREADS) void knn10_k(const float* __restrict__ pts,
    int* __restrict__ out_idx, float* __restrict__ out_dirn)
{
  constexpr int CHUNK = VC/64;
  constexpr int QPB = THREADS/64;
  constexpr int TOT = 11;
  __shared__ float4v sp4[VC];
  int t = threadIdx.x;
  int lane = t & 63;
  int wv   = t >> 6;
  int b = blockIdx.y;
  int j = blockIdx.x*QPB + wv;
  const float* pb = pts + (size_t)b*VC*3;
  for(int i=t; i<VC; i+=THREADS){
    float x=pb[3*i], y=pb[3*i+1], z=pb[3*i+2];
    float4v v; v[0]=x; v[1]=y; v[2]=z; v[3]=x*x+y*y+z*z;
    sp4[i]=v;
  }
  __syncthreads();
  float qx=pb[3*j], qy=pb[3*j+1], qz=pb[3*j+2];
  float qs=qx*qx+qy*qy+qz*qz;

  u64 p0=~0ull,p1=~0ull,p2=~0ull,p3=~0ull;
  #pragma unroll 4
  for(int c=0;c<CHUNK;c++){
    int i = c*64 + lane;
    float4v p = sp4[i];
    float dot = qx*p[0]+qy*p[1]+qz*p[2];
    float d = fmaf(-2.0f, dot, p[3]+qs);
    u64 k = ((u64)fkey(d)<<32) | (unsigned int)i;
    // wave-uniform skip: most candidates beat nobody's 4th-best
    if(__any(k < p3)){
      p3 = k<p3 ? k : p3;
      { u64 a=p2<p3?p2:p3, q=p2<p3?p3:p2; p2=a; p3=q; }
      { u64 a=p1<p2?p1:p2, q=p1<p2?p2:p1; p1=a; p2=q; }
      { u64 a=p0<p1?p0:p1, q=p0<p1?p1:p0; p0=a; p1=q; }
    }
  }
  // extraction: 11 rounds of wave-argmin over "smallest pool entry > prev"
  u64 prev=0ull, wkey=0ull;
  for(int sel=0; sel<TOT; ++sel){
    u64 c = p0>prev?p0:(p1>prev?p1:(p2>prev?p2:(p3>prev?p3:~0ull)));
    #pragma unroll
    for(int s=32;s;s>>=1){
      u64 o = shfl_xor_u64(c,s);
      c = o<c ? o : c;
    }
    if(lane==sel) wkey=c;
    prev=c;
  }
  // exactness guard: lane's pool exhausted at/below the 11th selected
  if(__any(p3<=prev)){
    prev=0ull;
    for(int sel=0; sel<TOT; ++sel){
      u64 c=~0ull;
      for(int cc=0;cc<CHUNK;cc++){
        int i=cc*64+lane;
        float4v p = sp4[i];
        float dot = qx*p[0]+qy*p[1]+qz*p[2];
        float d = fmaf(-2.0f, dot, p[3]+qs);
        u64 k = ((u64)fkey(d)<<32) | (unsigned int)i;
        if(k>prev && k<c) c=k;
      }
      #pragma unroll
      for(int s=32;s;s>>=1){
        u64 o = shfl_xor_u64(c,s);
        c = o<c ? o : c;
      }
      if(lane==sel) wkey=c;
      prev=c;
    }
  }
  if(lane>=1 && lane<TOT){
    int wi=(int)(wkey & 0xffffffffu);
    size_t obase=((size_t)b*VC+j)*10 + (lane-1);
    out_idx[obase]=wi;
    float4v p = sp4[wi];
    float dx=p[0]-qx, dy=p[1]-qy, dz=p[2]-qz;
    float n=sqrtf(dx*dx+dy*dy+dz*dz); n=fmaxf(n,1e-12f);
    out_dirn[obase*3]=dx/n; out_dirn[obase*3+1]=dy/n; out_dirn[obase*3+2]=dz/n;
  }
}

// ---------------- fused nearest for v1 and v2 (argmin, ties -> lower index) ----------
__global__ __launch_bounds__(512) void nearest_both_k(
    const float* __restrict__ v1, const float* __restrict__ v2,
    const float* __restrict__ x,
    int* __restrict__ n1, int* __restrict__ n2)
{
  __shared__ float4v s1[V1N];
  __shared__ float4v s2[V2N];
  int t=threadIdx.x;
  int lane=t&63, wv=t>>6;
  int b=blockIdx.y; int j=blockIdx.x*8+wv;
  const float* c1=v1+(size_t)b*V1N*3;
  const float* c2=v2+(size_t)b*V2N*3;
  for(int i=t;i<V1N;i+=512){
    float xx=c1[3*i],yy=c1[3*i+1],zz=c1[3*i+2];
    float4v v; v[0]=xx;v[1]=yy;v[2]=zz;v[3]=xx*xx+yy*yy+zz*zz; s1[i]=v;
  }
  for(int i=t;i<V2N;i+=512){
    float xx=c2[3*i],yy=c2[3*i+1],zz=c2[3*i+2];
    float4v v; v[0]=xx;v[1]=yy;v[2]=zz;v[3]=xx*xx+yy*yy+zz*zz; s2[i]=v;
  }
  __syncthreads();
  const float* qb=x+(size_t)b*V0*3;
  float qx=qb[3*j],qy=qb[3*j+1],qz=qb[3*j+2];
  float qs=qx*qx+qy*qy+qz*qz;
  u64 bk=~0ull;
  #pragma unroll 4
  for(int c=0;c<V1N/64;c++){
    int i=c*64+lane;
    float4v p=s1[i];
    float dot=qx*p[0]+qy*p[1]+qz*p[2];
    float d=fmaf(-2.0f,dot,p[3]+qs);
    u64 k=((u64)fkey(d)<<32)|(unsigned int)i;
    bk = k<bk ? k : bk;
  }
  #pragma unroll
  for(int s=32;s;s>>=1){ u64 o=shfl_xor_u64(bk,s); bk = o<bk?o:bk; }
  if(lane==0) n1[(size_t)b*V0+j]=(int)(bk&0xffffffffu);
  bk=~0ull;
  #pragma unroll 4
  for(int c=0;c<V2N/64;c++){
    int i=c*64+lane;
    float4v p=s2[i];
    float dot=qx*p[0]+qy*p[1]+qz*p[2];
    float d=fmaf(-2.0f,dot,p[3]+qs);
    u64 k=((u64)fkey(d)<<32)|(unsigned int)i;
    bk = k<bk ? k : bk;
  }
  #pragma unroll
  for(int s=32;s;s>>=1){ u64 o=shfl_xor_u64(bk,s); bk = o<bk?o:bk; }
  if(lane==0) n2[(size_t)b*V0+j]=(int)(bk&0xffffffffu);
}

// ---------------- conv_surface + outer silu -> fm0 + out[:, :128] ----------------
template<int NODES>
__global__ __launch_bounds__(64*NODES) void conv_surf_k(
    const float* __restrict__ dirn, const float* __restrict__ cnd,
    float* __restrict__ fm0, float* __restrict__ outbuf)
{
  int tid=threadIdx.x, nd=tid>>6, t=tid&63;
  int b=blockIdx.y, i=blockIdx.x*NODES+nd;
  __shared__ float sd[NODES][32];
  if(t<30) sd[nd][t]=dirn[((size_t)(b*V0+i))*30+t];
  __syncthreads();
  float acc0=0.0f, acc1=0.0f;
  for(int s=0;s<SUPN;s++){
    int col=s*128+t;
    float wa0=cnd[col],     wa1=cnd[896+col],     wa2=cnd[1792+col];
    float wb0=cnd[col+64],  wb1=cnd[896+col+64],  wb2=cnd[1792+col+64];
    float m0=-INFINITY, m1=-INFINITY;
    #pragma unroll
    for(int n=0;n<10;n++){
      float dx=sd[nd][3*n], dy=sd[nd][3*n+1], dz=sd[nd][3*n+2];
      m0=fmaxf(m0, fast_silu(dx*wa0+dy*wa1+dz*wa2));
      m1=fmaxf(m1, fast_silu(dx*wb0+dy*wb1+dz*wb2));
    }
    acc0+=m0; acc1+=m1;
  }
  float r0=fast_silu(acc0), r1=fast_silu(acc1);
  size_t frow=(size_t)(b*V0+i)*128;
  fm0[frow+t]=r0; fm0[frow+64+t]=r1;
  size_t orow=(size_t)(b*V0+i)*1280;
  outbuf[orow+t]=r0; outbuf[orow+64+t]=r1;
}

// ---------------- GEMM: C[M,N] = A[M,K] @ W[K,N] + bias[N] (128x128, 8x8/thr) ----
__global__ __launch_bounds__(256) void gemm_bias_k(
    const float* __restrict__ A, const float* __restrict__ W,
    const float* __restrict__ bias, float* __restrict__ C,
    int M, int N, int K)
{
  __shared__ float As[16][132];
  __shared__ float Bs[16][132];
  int t=threadIdx.x;
  int tx=t&15, ty=t>>4;
  int bm=blockIdx.y*128, bn=blockIdx.x*128;
  float4v acc[2][2][4];
  #pragma unroll
  for(int a=0;a<2;a++)
    #pragma unroll
    for(int bidx=0;bidx<2;bidx++)
      #pragma unroll
      for(int m=0;m<4;m++) acc[a][bidx][m]=(float4v)(0.0f);
  int arow=t>>2, akk=(t&3)*4;
  int brow=t>>4, bcol=(t&15)*4;
  for(int k0=0;k0<K;k0+=16){
    float4v a0=*(const float4v*)&A[(size_t)(bm+arow)*K    + k0+akk];
    float4v a1=*(const float4v*)&A[(size_t)(bm+64+arow)*K + k0+akk];
    float4v b0=*(const float4v*)&W[(size_t)(k0+brow)*N + bn+bcol];
    float4v b1=*(const float4v*)&W[(size_t)(k0+brow)*N + bn+64+bcol];
    __syncthreads();
    #pragma unroll
    for(int u=0;u<4;u++){ As[akk+u][arow]=a0[u]; As[akk+u][64+arow]=a1[u]; }
    *(float4v*)&Bs[brow][bcol]=b0;
    *(float4v*)&Bs[brow][64+bcol]=b1;
    __syncthreads();
    #pragma unroll
    for(int kk=0;kk<16;kk++){
      float4v alo=*(const float4v*)&As[kk][ty*4];
      float4v ahi=*(const float4v*)&As[kk][64+ty*4];
      float4v blo=*(const float4v*)&Bs[kk][tx*4];
      float4v bhi=*(const float4v*)&Bs[kk][64+tx*4];
      #pragma unroll
      for(int mi=0;mi<4;mi++){
        acc[0][0][mi] += alo[mi]*blo;
        acc[0][1][mi] += alo[mi]*bhi;
        acc[1][0][mi] += ahi[mi]*blo;
        acc[1][1][mi] += ahi[mi]*bhi;
      }
    }
  }
  float4v bl=*(const float4v*)&bias[bn+tx*4];
  float4v bh=*(const float4v*)&bias[bn+64+tx*4];
  #pragma unroll
  for(int mh=0;mh<2;mh++)
    #pragma unroll
    for(int mi=0;mi<4;mi++){
      size_t row=(size_t)(bm+mh*64+ty*4+mi);
      *(float4v*)&C[row*N + bn+tx*4]    = acc[mh][0][mi]+bl;
      *(float4v*)&C[row*N + bn+64+tx*4] = acc[mh][1][mi]+bh;
    }
}

// ---------------- conv_layer aggregate + fused BN-stats epilogue ----------------
template<int C, int TPN, int NODES>
__global__ __launch_bounds__(TPN*NODES) void conv_agg_k(
    const float* __restrict__ feat, int Vb,
    const float* __restrict__ dirn, const int* __restrict__ nbidx,
    const float* __restrict__ cnd,
    float* __restrict__ outp, float* __restrict__ stats)
{
  constexpr int NC = 8*C;
  constexpr int VEC = C/TPN;
  constexpr int ncol = SUPN*C;
  constexpr int NT = TPN*NODES;
  int tid=threadIdx.x, nd=tid/TPN, t=tid%TPN;
  int b=blockIdx.y, i=blockIdx.x*NODES+nd;
  __shared__ float sd[NODES][32];
  __shared__ int snb[NODES][12];
  __shared__ float ssum[C], ssq[C];
  if(t<30) sd[nd][t]=dirn[((size_t)(b*Vb+i))*30+t];
  if(t<10) snb[nd][t]=nbidx[(size_t)(b*Vb+i)*10+t];
  for(int c=tid;c<C;c+=NT){ ssum[c]=0.0f; ssq[c]=0.0f; }
  __syncthreads();
  float acc[VEC];
  {
    const float* cptr=&feat[(size_t)(b*Vb+i)*NC + t*VEC];
    if(VEC==4){ float4v cv=*(const float4v*)cptr;
      #pragma unroll
      for(int v=0;v<4;v++) acc[v]=cv[v];
    } else { float2v cv=*(const float2v*)cptr;
      #pragma unroll
      for(int v=0;v<VEC;v++) acc[v]=cv[v];
    }
  }
  const float* fb=feat+(size_t)b*Vb*NC;
  for(int s=0;s<SUPN;s++){
    int colbase = s*C + t*VEC;
    float w0[VEC],w1[VEC],w2[VEC],m[VEC];
    #pragma unroll
    for(int v=0;v<VEC;v++){
      w0[v]=cnd[colbase+v]; w1[v]=cnd[ncol+colbase+v]; w2[v]=cnd[2*ncol+colbase+v];
      m[v]=-INFINITY;
    }
    #pragma unroll
    for(int n=0;n<10;n++){
      float dx=sd[nd][3*n],dy=sd[nd][3*n+1],dz=sd[nd][3*n+2];
      const float* sptr=&fb[(size_t)snb[nd][n]*NC + C + colbase];
      float sup[VEC];
      if(VEC==4){
        float4v sv=*(const float4v*)sptr;
        #pragma unroll
        for(int v=0;v<4;v++) sup[v]=sv[v];
      } else {
        float2v sv=*(const float2v*)sptr;
        #pragma unroll
        for(int v=0;v<VEC;v++) sup[v]=sv[v];
      }
      #pragma unroll
      for(int v=0;v<VEC;v++){
        float d=dx*w0[v]+dy*w1[v]+dz*w2[v];
        m[v]=fmaxf(m[v], fast_silu(d)*sup[v]);
      }
    }
    #pragma unroll
    for(int v=0;v<VEC;v++) acc[v]+=m[v];
  }
  float* optr=&outp[(size_t)(b*Vb+i)*C + t*VEC];
  if(VEC==4){ float4v ov;
    #pragma unroll
    for(int v=0;v<4;v++) ov[v]=acc[v];
    *(float4v*)optr=ov;
  } else { float2v ov;
    #pragma unroll
    for(int v=0;v<VEC;v++) ov[v]=acc[v];
    *(float2v*)optr=ov;
  }
  if(stats){
    #pragma unroll
    for(int v=0;v<VEC;v++){
      atomicAdd(&ssum[t*VEC+v], acc[v]);
      atomicAdd(&ssq[t*VEC+v], acc[v]*acc[v]);
    }
    __syncthreads();
    for(int c=tid;c<C;c+=NT){
      atomicAdd(&stats[c], ssum[c]);
      atomicAdd(&stats[C+c], ssq[c]);
    }
  }
}

// ---------------- BN apply + silu, float4 (+ optional out-slice write) ----------------
__global__ void bn_silu_k(const float* __restrict__ xin, const float* __restrict__ sums,
                          float invM, int C, const float* __restrict__ g, const float* __restrict__ bb,
                          float* __restrict__ y, int nquad, float* __restrict__ osl, int cshift)
{
  int gid=blockIdx.x*blockDim.x+threadIdx.x;
  if(gid>=nquad) return;
  int base=gid*4;
  int c=base&(C-1);
  float4v xv=*(const float4v*)&xin[base];
  float4v sm=*(const float4v*)&sums[c];
  float4v sq=*(const float4v*)&sums[C+c];
  float4v gv=*(const float4v*)&g[c];
  float4v bv=*(const float4v*)&bb[c];
  float4v r;
  #pragma unroll
  for(int u=0;u<4;u++){
    float mean=sm[u]*invM;
    float var=sq[u]*invM - mean*mean;
    float v=(xv[u]-mean)*rsqrtf(var+1e-5f)*gv[u]+bv[u];
    r[u]=fast_silu(v);
  }
  *(float4v*)&y[base]=r;
  if(osl){
    int row=base>>cshift;
    *(float4v*)&osl[(size_t)row*1280 + c]=r;
  }
}

// ---------------- pool over first-4 of idx10 at perm rows + coord gather (float4) ----
template<int C, int NODES>
__global__ __launch_bounds__((C/4)*NODES) void pool_gather_k(
    const float* __restrict__ fm, int Vsrc,
    const int* __restrict__ idx10, const int* __restrict__ perm,
    const float* __restrict__ vsrc,
    float* __restrict__ fout, float* __restrict__ vout, int Vq)
{
  constexpr int TPN=C/4;
  int tid=threadIdx.x, nd=tid/TPN, t=tid%TPN;
  int b=blockIdx.y, j=blockIdx.x*NODES+nd;
  int r=perm[j];
  const int* id=idx10+((size_t)b*Vsrc+r)*10;
  const float* fb=fm+(size_t)b*Vsrc*C;
  float4v m=(float4v)(-INFINITY);
  #pragma unroll
  for(int n=0;n<4;n++){
    float4v fv=*(const float4v*)&fb[(size_t)id[n]*C + t*4];
    #pragma unroll
    for(int u=0;u<4;u++) m[u]=fmaxf(m[u],fv[u]);
  }
  *(float4v*)&fout[(size_t)(b*Vq+j)*C + t*4]=m;
  if(t<3) vout[((size_t)b*Vq+j)*3+t]=vsrc[((size_t)b*Vsrc+r)*3+t];
}

// ---------------- final concat: only fm2/fm3/fm4 upsampled slices ----------------
__global__ __launch_bounds__(256) void concat_k(
    const float* __restrict__ fm2, const float* __restrict__ fm3,
    const float* __restrict__ fm4,
    const int* __restrict__ n1, const int* __restrict__ n2,
    float* __restrict__ outp)
{
  int b=blockIdx.y, i=blockIdx.x, t=threadIdx.x;
  int j1=n1[b*V0+i], j2=n2[b*V0+i];
  float4v v;
  if(t<64)       v = ((const float4v*)(fm2 + ((size_t)b*V1N+j1)*256))[t];
  else if(t<128) v = ((const float4v*)(fm3 + ((size_t)b*V1N+j1)*256))[t-64];
  else           v = ((const float4v*)(fm4 + ((size_t)b*V2N+j2)*512))[t-128];
  ((float4v*)(outp + (size_t)(b*V0+i)*1280))[64+t] = v;
}

extern "C" void kernel_launch(void* const* d_in, const int* in_sizes, int n_in,
                              void* d_out, int out_size, void* d_ws, size_t ws_size,
                              hipStream_t stream) {
  const float* x   =(const float*)d_in[0];
  const float* d0  =(const float*)d_in[1];
  const float* w1  =(const float*)d_in[2];
  const float* b1  =(const float*)d_in[3];
  const float* dir1=(const float*)d_in[4];
  const float* g1  =(const float*)d_in[5];
  const float* bb1 =(const float*)d_in[6];
  const float* w2  =(const float*)d_in[7];
  const float* b2  =(const float*)d_in[8];
  const float* dir2=(const float*)d_in[9];
  const float* g2  =(const float*)d_in[10];
  const float* bb2 =(const float*)d_in[11];
  const float* w3  =(const float*)d_in[12];
  const float* b3  =(const float*)d_in[13];
  const float* dir3=(const float*)d_in[14];
  const float* g3  =(const float*)d_in[15];
  const float* bb3 =(const float*)d_in[16];
  const float* w4  =(const float*)d_in[17];
  const float* b4  =(const float*)d_in[18];
  const float* dir4=(const float*)d_in[19];
  const int* perm1 =(const int*)d_in[20];
  const int* perm2 =(const int*)d_in[21];
  float* out=(float*)d_out;

  float* w=(float*)d_ws;
  size_t off=0;
  auto alloc=[&](size_t n){ float* p=w+off; off+=n; return p; };
  float* cn0 =alloc(2688);
  float* cn1 =alloc(2688);
  float* cn2 =alloc(5376);
  float* cn3 =alloc(5376);
  float* cn4 =alloc(10752);
  float* dirnx =alloc((size_t)BNUM*V0*30);
  float* dirnv1=alloc((size_t)BNUM*V1N*30);
  float* dirnv2=alloc((size_t)BNUM*V2N*30);
  float* fm0 =alloc((size_t)BNUM*V0*128);
  float* feat=alloc((size_t)BNUM*V0*1024);
  float* fm1r=alloc((size_t)BNUM*V0*128);
  float* fm1 =alloc((size_t)BNUM*V0*128);
  float* f1  =alloc((size_t)BNUM*V1N*128);
  float* v1  =alloc((size_t)BNUM*V1N*3);
  float* fm2r=alloc((size_t)BNUM*V1N*256);
  float* fm2 =alloc((size_t)BNUM*V1N*256);
  float* fm3r=alloc((size_t)BNUM*V1N*256);
  float* fm3 =alloc((size_t)BNUM*V1N*256);
  float* f2  =alloc((size_t)BNUM*V2N*256);
  float* v2  =alloc((size_t)BNUM*V2N*3);
  float* fm4 =alloc((size_t)BNUM*V2N*512);
  float* stats=alloc(1280);
  int* idx10x =(int*)alloc((size_t)BNUM*V0*10);
  int* idx10v1=(int*)alloc((size_t)BNUM*V1N*10);
  int* idx10v2=(int*)alloc((size_t)BNUM*V2N*10);
  int* n1i =(int*)alloc((size_t)BNUM*V0);
  int* n2i =(int*)alloc((size_t)BNUM*V0);

  colnorm_all_k<<<dim3(35),256,0,stream>>>(d0,dir1,dir2,dir3,dir4,cn0,cn1,cn2,cn3,cn4,stats);

  // knn10 on x
  knn10_k<V0,1024><<<dim3(V0/16,BNUM),1024,0,stream>>>(x, idx10x, dirnx);
  // fm0 = silu(conv_surface) -> fm0 scratch + out[:, :128]
  conv_surf_k<4><<<dim3(V0/4,BNUM),256,0,stream>>>(dirnx, cn0, fm0, out);

  // layer 1
  gemm_bias_k<<<dim3(1024/128,(BNUM*V0)/128),256,0,stream>>>(fm0, w1, b1, feat, BNUM*V0, 1024, 128);
  conv_agg_k<128,64,4><<<dim3(V0/4,BNUM),256,0,stream>>>(feat, V0, dirnx, idx10x, cn1, fm1r, stats);
  bn_silu_k<<<dim3((BNUM*V0*128/4)/256),256,0,stream>>>(fm1r, stats, 1.0f/(BNUM*V0), 128, g1, bb1, fm1, BNUM*V0*128/4, out+128, 7);

  // pool (first-4 of idx10x at perm1) + v1 gather
  pool_gather_k<128,8><<<dim3(V1N/8,BNUM),256,0,stream>>>(fm1, V0, idx10x, perm1, x, f1, v1, V1N);

  // knn10 on v1
  knn10_k<V1N,256><<<dim3(V1N/4,BNUM),256,0,stream>>>(v1, idx10v1, dirnv1);

  // layer 2
  gemm_bias_k<<<dim3(2048/128,(BNUM*V1N)/128),256,0,stream>>>(f1, w2, b2, feat, BNUM*V1N, 2048, 128);
  conv_agg_k<256,64,4><<<dim3(V1N/4,BNUM),256,0,stream>>>(feat, V1N, dirnv1, idx10v1, cn2, fm2r, stats+256);
  bn_silu_k<<<dim3((BNUM*V1N*256/4)/256),256,0,stream>>>(fm2r, stats+256, 1.0f/(BNUM*V1N), 256, g2, bb2, fm2, BNUM*V1N*256/4, nullptr, 8);

  // layer 3
  gemm_bias_k<<<dim3(2048/128,(BNUM*V1N)/128),256,0,stream>>>(fm2, w3, b3, feat, BNUM*V1N, 2048, 256);
  conv_agg_k<256,64,4><<<dim3(V1N/4,BNUM),256,0,stream>>>(feat, V1N, dirnv1, idx10v1, cn3, fm3r, stats+768);
  bn_silu_k<<<dim3((BNUM*V1N*256/4)/256),256,0,stream>>>(fm3r, stats+768, 1.0f/(BNUM*V1N), 256, g3, bb3, fm3, BNUM*V1N*256/4, nullptr, 8);

  // pool (first-4 of idx10v1 at perm2) + v2 gather
  pool_gather_k<256,4><<<dim3(V2N/4,BNUM),256,0,stream>>>(fm3, V1N, idx10v1, perm2, v1, f2, v2, V2N);

  // knn10 on v2
  knn10_k<V2N,256><<<dim3(V2N/4,BNUM),256,0,stream>>>(v2, idx10v2, dirnv2);

  // layer 4 (no bn/silu)
  gemm_bias_k<<<dim3(4096/128,(BNUM*V2N)/128),256,0,stream>>>(f2, w4, b4, feat, BNUM*V2N, 4096, 256);
  conv_agg_k<512,128,2><<<dim3(V2N/2,BNUM),256,0,stream>>>(feat, V2N, dirnv2, idx10v2, cn4, fm4, nullptr);

  // fused nearest upsample indices
  nearest_both_k<<<dim3(V0/8,BNUM),512,0,stream>>>(v1, v2, x, n1i, n2i);

  // final concat (fm2/fm3/fm4 slices only)
  concat_k<<<dim3(V0,BNUM),256,0,stream>>>(fm2, fm3, fm4, n1i, n2i, out);
}

// Round 7
// 565.623 us; speedup vs baseline: 1.3982x; 1.0189x over previous
//
#include <hip/hip_runtime.h>
#include <math.h>
#include <float.h>
#include <limits.h>

#define BNUM 2
#define V0 4096
#define V1N 1024
#define V2N 256
#define SUPN 7

typedef float float4v __attribute__((ext_vector_type(4)));
typedef float float2v __attribute__((ext_vector_type(2)));
typedef unsigned short ushort4v __attribute__((ext_vector_type(4)));
typedef unsigned long long u64;

__device__ __forceinline__ float fast_silu(float x){
  return __fdividef(x, 1.0f + __expf(-x));
}

// RNE float -> bf16
__device__ __forceinline__ unsigned short f2bf(float f){
  unsigned int u=__float_as_uint(f);
  u += 0x7FFFu + ((u>>16)&1u);
  return (unsigned short)(u>>16);
}
__device__ __forceinline__ float bf2f(unsigned short h){
  return __uint_as_float(((unsigned int)h)<<16);
}

// exact monotone float->uint transform
__device__ __forceinline__ unsigned int fkey(float f){
  unsigned int u = __float_as_uint(f);
  int m = ((int)u) >> 31;
  return u ^ (unsigned int)(m | 0x80000000);
}

__device__ __forceinline__ u64 shfl_xor_u64(u64 v, int m){
  unsigned int lo = (unsigned int)v, hi = (unsigned int)(v>>32);
  lo = (unsigned int)__shfl_xor((int)lo, m);
  hi = (unsigned int)__shfl_xor((int)hi, m);
  return ((u64)hi<<32) | lo;
}

// ---------------- fused column-normalize + stats zero ----------------
__global__ void colnorm_all_k(const float* __restrict__ d0, const float* __restrict__ dir1,
                              const float* __restrict__ dir2, const float* __restrict__ dir3,
                              const float* __restrict__ dir4,
                              float* __restrict__ cn0, float* __restrict__ cn1,
                              float* __restrict__ cn2, float* __restrict__ cn3,
                              float* __restrict__ cn4, float* __restrict__ stats){
  int c = blockIdx.x*256 + threadIdx.x;
  if(c < 1280) stats[c] = 0.0f;
  const float* s; float* o; int nc;
  if(c < 896){ s=d0; o=cn0; nc=896; }
  else if((c-=896) < 896){ s=dir1; o=cn1; nc=896; }
  else if((c-=896) < 1792){ s=dir2; o=cn2; nc=1792; }
  else if((c-=1792) < 1792){ s=dir3; o=cn3; nc=1792; }
  else { c-=1792; if(c>=3584) return; s=dir4; o=cn4; nc=3584; }
  float a=s[c], b=s[nc+c], e=s[2*nc+c];
  float n=sqrtf(a*a+b*b+e*e); n=fmaxf(n,1e-12f);
  o[c]=a/n; o[nc+c]=b/n; o[2*nc+c]=e/n;
}

// ---------------- self-KNN (k=10, skip self), u64 keys + guarded insert ----------------
template<int VC, int THREADS>
__global__ __launch_bounds__(THREADS) void knn10_k(const float* __restrict__ pts,
    int* __restrict__ out_idx, float* __restrict__ out_dirn)
{
  constexpr int CHUNK = VC/64;
  constexpr int QPB = THREADS/64;
  constexpr int TOT = 11;
  __shared__ float4v sp4[VC];
  int t = threadIdx.x;
  int lane = t & 63;
  int wv   = t >> 6;
  int b = blockIdx.y;
  int j = blockIdx.x*QPB + wv;
  const float* pb = pts + (size_t)b*VC*3;
  for(int i=t; i<VC; i+=THREADS){
    float x=pb[3*i], y=pb[3*i+1], z=pb[3*i+2];
    float4v v; v[0]=x; v[1]=y; v[2]=z; v[3]=x*x+y*y+z*z;
    sp4[i]=v;
  }
  __syncthreads();
  float qx=pb[3*j], qy=pb[3*j+1], qz=pb[3*j+2];
  float qs=qx*qx+qy*qy+qz*qz;

  u64 p0=~0ull,p1=~0ull,p2=~0ull,p3=~0ull;
  #pragma unroll 4
  for(int c=0;c<CHUNK;c++){
    int i = c*64 + lane;
    float4v p = sp4[i];
    float dot = qx*p[0]+qy*p[1]+qz*p[2];
    float d = fmaf(-2.0f, dot, p[3]+qs);
    u64 k = ((u64)fkey(d)<<32) | (unsigned int)i;
    if(__any(k < p3)){
      p3 = k<p3 ? k : p3;
      { u64 a=p2<p3?p2:p3, q=p2<p3?p3:p2; p2=a; p3=q; }
      { u64 a=p1<p2?p1:p2, q=p1<p2?p2:p1; p1=a; p2=q; }
      { u64 a=p0<p1?p0:p1, q=p0<p1?p1:p0; p0=a; p1=q; }
    }
  }
  u64 prev=0ull, wkey=0ull;
  for(int sel=0; sel<TOT; ++sel){
    u64 c = p0>prev?p0:(p1>prev?p1:(p2>prev?p2:(p3>prev?p3:~0ull)));
    #pragma unroll
    for(int s=32;s;s>>=1){
      u64 o = shfl_xor_u64(c,s);
      c = o<c ? o : c;
    }
    if(lane==sel) wkey=c;
    prev=c;
  }
  if(__any(p3<=prev)){
    prev=0ull;
    for(int sel=0; sel<TOT; ++sel){
      u64 c=~0ull;
      for(int cc=0;cc<CHUNK;cc++){
        int i=cc*64+lane;
        float4v p = sp4[i];
        float dot = qx*p[0]+qy*p[1]+qz*p[2];
        float d = fmaf(-2.0f, dot, p[3]+qs);
        u64 k = ((u64)fkey(d)<<32) | (unsigned int)i;
        if(k>prev && k<c) c=k;
      }
      #pragma unroll
      for(int s=32;s;s>>=1){
        u64 o = shfl_xor_u64(c,s);
        c = o<c ? o : c;
      }
      if(lane==sel) wkey=c;
      prev=c;
    }
  }
  if(lane>=1 && lane<TOT){
    int wi=(int)(wkey & 0xffffffffu);
    size_t obase=((size_t)b*VC+j)*10 + (lane-1);
    out_idx[obase]=wi;
    float4v p = sp4[wi];
    float dx=p[0]-qx, dy=p[1]-qy, dz=p[2]-qz;
    float n=sqrtf(dx*dx+dy*dy+dz*dz); n=fmaxf(n,1e-12f);
    out_dirn[obase*3]=dx/n; out_dirn[obase*3+1]=dy/n; out_dirn[obase*3+2]=dz/n;
  }
}

// ---------------- fused nearest for v1 and v2 ----------
__global__ __launch_bounds__(512) void nearest_both_k(
    const float* __restrict__ v1, const float* __restrict__ v2,
    const float* __restrict__ x,
    int* __restrict__ n1, int* __restrict__ n2)
{
  __shared__ float4v s1[V1N];
  __shared__ float4v s2[V2N];
  int t=threadIdx.x;
  int lane=t&63, wv=t>>6;
  int b=blockIdx.y; int j=blockIdx.x*8+wv;
  const float* c1=v1+(size_t)b*V1N*3;
  const float* c2=v2+(size_t)b*V2N*3;
  for(int i=t;i<V1N;i+=512){
    float xx=c1[3*i],yy=c1[3*i+1],zz=c1[3*i+2];
    float4v v; v[0]=xx;v[1]=yy;v[2]=zz;v[3]=xx*xx+yy*yy+zz*zz; s1[i]=v;
  }
  for(int i=t;i<V2N;i+=512){
    float xx=c2[3*i],yy=c2[3*i+1],zz=c2[3*i+2];
    float4v v; v[0]=xx;v[1]=yy;v[2]=zz;v[3]=xx*xx+yy*yy+zz*zz; s2[i]=v;
  }
  __syncthreads();
  const float* qb=x+(size_t)b*V0*3;
  float qx=qb[3*j],qy=qb[3*j+1],qz=qb[3*j+2];
  float qs=qx*qx+qy*qy+qz*qz;
  u64 bk=~0ull;
  #pragma unroll 4
  for(int c=0;c<V1N/64;c++){
    int i=c*64+lane;
    float4v p=s1[i];
    float dot=qx*p[0]+qy*p[1]+qz*p[2];
    float d=fmaf(-2.0f,dot,p[3]+qs);
    u64 k=((u64)fkey(d)<<32)|(unsigned int)i;
    bk = k<bk ? k : bk;
  }
  #pragma unroll
  for(int s=32;s;s>>=1){ u64 o=shfl_xor_u64(bk,s); bk = o<bk?o:bk; }
  if(lane==0) n1[(size_t)b*V0+j]=(int)(bk&0xffffffffu);
  bk=~0ull;
  #pragma unroll 4
  for(int c=0;c<V2N/64;c++){
    int i=c*64+lane;
    float4v p=s2[i];
    float dot=qx*p[0]+qy*p[1]+qz*p[2];
    float d=fmaf(-2.0f,dot,p[3]+qs);
    u64 k=((u64)fkey(d)<<32)|(unsigned int)i;
    bk = k<bk ? k : bk;
  }
  #pragma unroll
  for(int s=32;s;s>>=1){ u64 o=shfl_xor_u64(bk,s); bk = o<bk?o:bk; }
  if(lane==0) n2[(size_t)b*V0+j]=(int)(bk&0xffffffffu);
}

// ---------------- conv_surface + outer silu -> fm0 + out[:, :128] ----------------
template<int NODES>
__global__ __launch_bounds__(64*NODES) void conv_surf_k(
    const float* __restrict__ dirn, const float* __restrict__ cnd,
    float* __restrict__ fm0, float* __restrict__ outbuf)
{
  int tid=threadIdx.x, nd=tid>>6, t=tid&63;
  int b=blockIdx.y, i=blockIdx.x*NODES+nd;
  __shared__ float sd[NODES][32];
  if(t<30) sd[nd][t]=dirn[((size_t)(b*V0+i))*30+t];
  __syncthreads();
  float acc0=0.0f, acc1=0.0f;
  for(int s=0;s<SUPN;s++){
    int col=s*128+t;
    float wa0=cnd[col],     wa1=cnd[896+col],     wa2=cnd[1792+col];
    float wb0=cnd[col+64],  wb1=cnd[896+col+64],  wb2=cnd[1792+col+64];
    float m0=-INFINITY, m1=-INFINITY;
    #pragma unroll
    for(int n=0;n<10;n++){
      float dx=sd[nd][3*n], dy=sd[nd][3*n+1], dz=sd[nd][3*n+2];
      m0=fmaxf(m0, fast_silu(dx*wa0+dy*wa1+dz*wa2));
      m1=fmaxf(m1, fast_silu(dx*wb0+dy*wb1+dz*wb2));
    }
    acc0+=m0; acc1+=m1;
  }
  float r0=fast_silu(acc0), r1=fast_silu(acc1);
  size_t frow=(size_t)(b*V0+i)*128;
  fm0[frow+t]=r0; fm0[frow+64+t]=r1;
  size_t orow=(size_t)(b*V0+i)*1280;
  outbuf[orow+t]=r0; outbuf[orow+64+t]=r1;
}

// ---------------- GEMM with split epilogue ----------------
// C = A@W + bias; columns < outC -> fp32 center buf (stride outC);
// columns >= outC -> bf16 support buf (stride 7*outC). Tiles are 128 wide so
// each tile is uniformly center or support (outC % 128 == 0).
__global__ __launch_bounds__(256) void gemm_split_k(
    const float* __restrict__ A, const float* __restrict__ W,
    const float* __restrict__ bias,
    float* __restrict__ Cc, unsigned short* __restrict__ Sp,
    int M, int N, int K, int outC)
{
  __shared__ float As[16][132];
  __shared__ float Bs[16][132];
  int t=threadIdx.x;
  int tx=t&15, ty=t>>4;
  int bm=blockIdx.y*128, bn=blockIdx.x*128;
  float4v acc[2][2][4];
  #pragma unroll
  for(int a=0;a<2;a++)
    #pragma unroll
    for(int bidx=0;bidx<2;bidx++)
      #pragma unroll
      for(int m=0;m<4;m++) acc[a][bidx][m]=(float4v)(0.0f);
  int arow=t>>2, akk=(t&3)*4;
  int brow=t>>4, bcol=(t&15)*4;
  for(int k0=0;k0<K;k0+=16){
    float4v a0=*(const float4v*)&A[(size_t)(bm+arow)*K    + k0+akk];
    float4v a1=*(const float4v*)&A[(size_t)(bm+64+arow)*K + k0+akk];
    float4v b0=*(const float4v*)&W[(size_t)(k0+brow)*N + bn+bcol];
    float4v b1=*(const float4v*)&W[(size_t)(k0+brow)*N + bn+64+bcol];
    __syncthreads();
    #pragma unroll
    for(int u=0;u<4;u++){ As[akk+u][arow]=a0[u]; As[akk+u][64+arow]=a1[u]; }
    *(float4v*)&Bs[brow][bcol]=b0;
    *(float4v*)&Bs[brow][64+bcol]=b1;
    __syncthreads();
    #pragma unroll
    for(int kk=0;kk<16;kk++){
      float4v alo=*(const float4v*)&As[kk][ty*4];
      float4v ahi=*(const float4v*)&As[kk][64+ty*4];
      float4v blo=*(const float4v*)&Bs[kk][tx*4];
      float4v bhi=*(const float4v*)&Bs[kk][64+tx*4];
      #pragma unroll
      for(int mi=0;mi<4;mi++){
        acc[0][0][mi] += alo[mi]*blo;
        acc[0][1][mi] += alo[mi]*bhi;
        acc[1][0][mi] += ahi[mi]*blo;
        acc[1][1][mi] += ahi[mi]*bhi;
      }
    }
  }
  float4v bl=*(const float4v*)&bias[bn+tx*4];
  float4v bh=*(const float4v*)&bias[bn+64+tx*4];
  if(bn + 128 <= outC){
    #pragma unroll
    for(int mh=0;mh<2;mh++)
      #pragma unroll
      for(int mi=0;mi<4;mi++){
        size_t row=(size_t)(bm+mh*64+ty*4+mi);
        *(float4v*)&Cc[row*outC + bn+tx*4]    = acc[mh][0][mi]+bl;
        *(float4v*)&Cc[row*outC + bn+64+tx*4] = acc[mh][1][mi]+bh;
      }
  } else {
    int sw = 7*outC;
    int scol = bn - outC;
    #pragma unroll
    for(int mh=0;mh<2;mh++)
      #pragma unroll
      for(int mi=0;mi<4;mi++){
        size_t row=(size_t)(bm+mh*64+ty*4+mi);
        float4v r0=acc[mh][0][mi]+bl, r1=acc[mh][1][mi]+bh;
        ushort4v p0,p1;
        #pragma unroll
        for(int u=0;u<4;u++){ p0[u]=f2bf(r0[u]); p1[u]=f2bf(r1[u]); }
        *(ushort4v*)&Sp[row*sw + scol+tx*4]    = p0;
        *(ushort4v*)&Sp[row*sw + scol+64+tx*4] = p1;
      }
  }
}

// ---------------- conv_layer aggregate (bf16 support gather) + BN-stats ----------------
template<int C, int TPN, int NODES>
__global__ __launch_bounds__(TPN*NODES) void conv_agg_k(
    const float* __restrict__ cent, const unsigned short* __restrict__ sup,
    int Vb,
    const float* __restrict__ dirn, const int* __restrict__ nbidx,
    const float* __restrict__ cnd,
    float* __restrict__ outp, float* __restrict__ stats)
{
  constexpr int ncol = SUPN*C;
  constexpr int NT = TPN*NODES;
  int tid=threadIdx.x, nd=tid/TPN, t=tid%TPN;
  int b=blockIdx.y, i=blockIdx.x*NODES+nd;
  __shared__ float sd[NODES][32];
  __shared__ int snb[NODES][12];
  __shared__ float ssum[C], ssq[C];
  if(t<30) sd[nd][t]=dirn[((size_t)(b*Vb+i))*30+t];
  if(t<10) snb[nd][t]=nbidx[(size_t)(b*Vb+i)*10+t];
  for(int c=tid;c<C;c+=NT){ ssum[c]=0.0f; ssq[c]=0.0f; }
  __syncthreads();
  float acc[4];
  {
    float4v cv=*(const float4v*)&cent[(size_t)(b*Vb+i)*C + t*4];
    #pragma unroll
    for(int v=0;v<4;v++) acc[v]=cv[v];
  }
  const unsigned short* fb=sup+(size_t)b*Vb*ncol;
  for(int s=0;s<SUPN;s++){
    int colbase = s*C + t*4;
    float w0[4],w1[4],w2[4],m[4];
    #pragma unroll
    for(int v=0;v<4;v++){
      w0[v]=cnd[colbase+v]; w1[v]=cnd[ncol+colbase+v]; w2[v]=cnd[2*ncol+colbase+v];
      m[v]=-INFINITY;
    }
    #pragma unroll
    for(int n=0;n<10;n++){
      float dx=sd[nd][3*n],dy=sd[nd][3*n+1],dz=sd[nd][3*n+2];
      ushort4v sv=*(const ushort4v*)&fb[(size_t)snb[nd][n]*ncol + colbase];
      #pragma unroll
      for(int v=0;v<4;v++){
        float d=dx*w0[v]+dy*w1[v]+dz*w2[v];
        m[v]=fmaxf(m[v], fast_silu(d)*bf2f(sv[v]));
      }
    }
    #pragma unroll
    for(int v=0;v<4;v++) acc[v]+=m[v];
  }
  {
    float4v ov;
    #pragma unroll
    for(int v=0;v<4;v++) ov[v]=acc[v];
    *(float4v*)&outp[(size_t)(b*Vb+i)*C + t*4]=ov;
  }
  if(stats){
    #pragma unroll
    for(int v=0;v<4;v++){
      atomicAdd(&ssum[t*4+v], acc[v]);
      atomicAdd(&ssq[t*4+v], acc[v]*acc[v]);
    }
    __syncthreads();
    for(int c=tid;c<C;c+=NT){
      atomicAdd(&stats[c], ssum[c]);
      atomicAdd(&stats[C+c], ssq[c]);
    }
  }
}

// ---------------- BN apply + silu, float4 (+ optional out-slice write) ----------------
__global__ void bn_silu_k(const float* __restrict__ xin, const float* __restrict__ sums,
                          float invM, int C, const float* __restrict__ g, const float* __restrict__ bb,
                          float* __restrict__ y, int nquad, float* __restrict__ osl, int cshift)
{
  int gid=blockIdx.x*blockDim.x+threadIdx.x;
  if(gid>=nquad) return;
  int base=gid*4;
  int c=base&(C-1);
  float4v xv=*(const float4v*)&xin[base];
  float4v sm=*(const float4v*)&sums[c];
  float4v sq=*(const float4v*)&sums[C+c];
  float4v gv=*(const float4v*)&g[c];
  float4v bv=*(const float4v*)&bb[c];
  float4v r;
  #pragma unroll
  for(int u=0;u<4;u++){
    float mean=sm[u]*invM;
    float var=sq[u]*invM - mean*mean;
    float v=(xv[u]-mean)*rsqrtf(var+1e-5f)*gv[u]+bv[u];
    r[u]=fast_silu(v);
  }
  *(float4v*)&y[base]=r;
  if(osl){
    int row=base>>cshift;
    *(float4v*)&osl[(size_t)row*1280 + c]=r;
  }
}

// ---------------- pool over first-4 of idx10 at perm rows + coord gather ----
template<int C, int NODES>
__global__ __launch_bounds__((C/4)*NODES) void pool_gather_k(
    const float* __restrict__ fm, int Vsrc,
    const int* __restrict__ idx10, const int* __restrict__ perm,
    const float* __restrict__ vsrc,
    float* __restrict__ fout, float* __restrict__ vout, int Vq)
{
  constexpr int TPN=C/4;
  int tid=threadIdx.x, nd=tid/TPN, t=tid%TPN;
  int b=blockIdx.y, j=blockIdx.x*NODES+nd;
  int r=perm[j];
  const int* id=idx10+((size_t)b*Vsrc+r)*10;
  const float* fb=fm+(size_t)b*Vsrc*C;
  float4v m=(float4v)(-INFINITY);
  #pragma unroll
  for(int n=0;n<4;n++){
    float4v fv=*(const float4v*)&fb[(size_t)id[n]*C + t*4];
    #pragma unroll
    for(int u=0;u<4;u++) m[u]=fmaxf(m[u],fv[u]);
  }
  *(float4v*)&fout[(size_t)(b*Vq+j)*C + t*4]=m;
  if(t<3) vout[((size_t)b*Vq+j)*3+t]=vsrc[((size_t)b*Vsrc+r)*3+t];
}

// ---------------- final concat: only fm2/fm3/fm4 upsampled slices ----------------
__global__ __launch_bounds__(256) void concat_k(
    const float* __restrict__ fm2, const float* __restrict__ fm3,
    const float* __restrict__ fm4,
    const int* __restrict__ n1, const int* __restrict__ n2,
    float* __restrict__ outp)
{
  int b=blockIdx.y, i=blockIdx.x, t=threadIdx.x;
  int j1=n1[b*V0+i], j2=n2[b*V0+i];
  float4v v;
  if(t<64)       v = ((const float4v*)(fm2 + ((size_t)b*V1N+j1)*256))[t];
  else if(t<128) v = ((const float4v*)(fm3 + ((size_t)b*V1N+j1)*256))[t-64];
  else           v = ((const float4v*)(fm4 + ((size_t)b*V2N+j2)*512))[t-128];
  ((float4v*)(outp + (size_t)(b*V0+i)*1280))[64+t] = v;
}

extern "C" void kernel_launch(void* const* d_in, const int* in_sizes, int n_in,
                              void* d_out, int out_size, void* d_ws, size_t ws_size,
                              hipStream_t stream) {
  const float* x   =(const float*)d_in[0];
  const float* d0  =(const float*)d_in[1];
  const float* w1  =(const float*)d_in[2];
  const float* b1  =(const float*)d_in[3];
  const float* dir1=(const float*)d_in[4];
  const float* g1  =(const float*)d_in[5];
  const float* bb1 =(const float*)d_in[6];
  const float* w2  =(const float*)d_in[7];
  const float* b2  =(const float*)d_in[8];
  const float* dir2=(const float*)d_in[9];
  const float* g2  =(const float*)d_in[10];
  const float* bb2 =(const float*)d_in[11];
  const float* w3  =(const float*)d_in[12];
  const float* b3  =(const float*)d_in[13];
  const float* dir3=(const float*)d_in[14];
  const float* g3  =(const float*)d_in[15];
  const float* bb3 =(const float*)d_in[16];
  const float* w4  =(const float*)d_in[17];
  const float* b4  =(const float*)d_in[18];
  const float* dir4=(const float*)d_in[19];
  const int* perm1 =(const int*)d_in[20];
  const int* perm2 =(const int*)d_in[21];
  float* out=(float*)d_out;

  float* w=(float*)d_ws;
  size_t off=0;
  auto alloc=[&](size_t n){ float* p=w+off; off+=n; return p; };
  float* cn0 =alloc(2688);
  float* cn1 =alloc(2688);
  float* cn2 =alloc(5376);
  float* cn3 =alloc(5376);
  float* cn4 =alloc(10752);
  float* dirnx =alloc((size_t)BNUM*V0*30);
  float* dirnv1=alloc((size_t)BNUM*V1N*30);
  float* dirnv2=alloc((size_t)BNUM*V2N*30);
  float* fm0 =alloc((size_t)BNUM*V0*128);
  float* cent=alloc((size_t)BNUM*V0*128);            // center cols (max 1M floats)
  unsigned short* supb=(unsigned short*)alloc((size_t)BNUM*V0*896/2); // bf16 support (max 7.34M ushort)
  float* fm1r=alloc((size_t)BNUM*V0*128);
  float* fm1 =alloc((size_t)BNUM*V0*128);
  float* f1  =alloc((size_t)BNUM*V1N*128);
  float* v1  =alloc((size_t)BNUM*V1N*3);
  float* fm2r=alloc((size_t)BNUM*V1N*256);
  float* fm2 =alloc((size_t)BNUM*V1N*256);
  float* fm3r=alloc((size_t)BNUM*V1N*256);
  float* fm3 =alloc((size_t)BNUM*V1N*256);
  float* f2  =alloc((size_t)BNUM*V2N*256);
  float* v2  =alloc((size_t)BNUM*V2N*3);
  float* fm4 =alloc((size_t)BNUM*V2N*512);
  float* stats=alloc(1280);
  int* idx10x =(int*)alloc((size_t)BNUM*V0*10);
  int* idx10v1=(int*)alloc((size_t)BNUM*V1N*10);
  int* idx10v2=(int*)alloc((size_t)BNUM*V2N*10);
  int* n1i =(int*)alloc((size_t)BNUM*V0);
  int* n2i =(int*)alloc((size_t)BNUM*V0);

  colnorm_all_k<<<dim3(35),256,0,stream>>>(d0,dir1,dir2,dir3,dir4,cn0,cn1,cn2,cn3,cn4,stats);

  // knn10 on x
  knn10_k<V0,1024><<<dim3(V0/16,BNUM),1024,0,stream>>>(x, idx10x, dirnx);
  // fm0 = silu(conv_surface) -> fm0 scratch + out[:, :128]
  conv_surf_k<4><<<dim3(V0/4,BNUM),256,0,stream>>>(dirnx, cn0, fm0, out);

  // layer 1 (C=128): GEMM 8192x1024x128
  gemm_split_k<<<dim3(1024/128,(BNUM*V0)/128),256,0,stream>>>(fm0, w1, b1, cent, supb, BNUM*V0, 1024, 128, 128);
  conv_agg_k<128,32,8><<<dim3(V0/8,BNUM),256,0,stream>>>(cent, supb, V0, dirnx, idx10x, cn1, fm1r, stats);
  bn_silu_k<<<dim3((BNUM*V0*128/4)/256),256,0,stream>>>(fm1r, stats, 1.0f/(BNUM*V0), 128, g1, bb1, fm1, BNUM*V0*128/4, out+128, 7);

  // pool (first-4 of idx10x at perm1) + v1 gather
  pool_gather_k<128,8><<<dim3(V1N/8,BNUM),256,0,stream>>>(fm1, V0, idx10x, perm1, x, f1, v1, V1N);

  // knn10 on v1
  knn10_k<V1N,256><<<dim3(V1N/4,BNUM),256,0,stream>>>(v1, idx10v1, dirnv1);

  // layer 2 (C=256): GEMM 2048x2048x128
  gemm_split_k<<<dim3(2048/128,(BNUM*V1N)/128),256,0,stream>>>(f1, w2, b2, cent, supb, BNUM*V1N, 2048, 128, 256);
  conv_agg_k<256,64,4><<<dim3(V1N/4,BNUM),256,0,stream>>>(cent, supb, V1N, dirnv1, idx10v1, cn2, fm2r, stats+256);
  bn_silu_k<<<dim3((BNUM*V1N*256/4)/256),256,0,stream>>>(fm2r, stats+256, 1.0f/(BNUM*V1N), 256, g2, bb2, fm2, BNUM*V1N*256/4, nullptr, 8);

  // layer 3 (C=256): GEMM 2048x2048x256
  gemm_split_k<<<dim3(2048/128,(BNUM*V1N)/128),256,0,stream>>>(fm2, w3, b3, cent, supb, BNUM*V1N, 2048, 256, 256);
  conv_agg_k<256,64,4><<<dim3(V1N/4,BNUM),256,0,stream>>>(cent, supb, V1N, dirnv1, idx10v1, cn3, fm3r, stats+768);
  bn_silu_k<<<dim3((BNUM*V1N*256/4)/256),256,0,stream>>>(fm3r, stats+768, 1.0f/(BNUM*V1N), 256, g3, bb3, fm3, BNUM*V1N*256/4, nullptr, 8);

  // pool (first-4 of idx10v1 at perm2) + v2 gather
  pool_gather_k<256,4><<<dim3(V2N/4,BNUM),256,0,stream>>>(fm3, V1N, idx10v1, perm2, v1, f2, v2, V2N);

  // knn10 on v2
  knn10_k<V2N,256><<<dim3(V2N/4,BNUM),256,0,stream>>>(v2, idx10v2, dirnv2);

  // layer 4 (C=512): GEMM 512x4096x256, no bn/silu
  gemm_split_k<<<dim3(4096/128,(BNUM*V2N)/128),256,0,stream>>>(f2, w4, b4, cent, supb, BNUM*V2N, 4096, 256, 512);
  conv_agg_k<512,128,2><<<dim3(V2N/2,BNUM),256,0,stream>>>(cent, supb, V2N, dirnv2, idx10v2, cn4, fm4, nullptr);

  // fused nearest upsample indices
  nearest_both_k<<<dim3(V0/8,BNUM),512,0,stream>>>(v1, v2, x, n1i, n2i);

  // final concat (fm2/fm3/fm4 slices only)
  concat_k<<<dim3(V0,BNUM),256,0,stream>>>(fm2, fm3, fm4, n1i, n2i, out);
}